// Round 13
// baseline (154.810 us; speedup 1.0000x reference)
//
#include <hip/hip_runtime.h>
#include <hip/hip_bf16.h>

#define BB 8
#define CC 512
#define NN 1024   // H*W
#define NG 32
#define CPG 16
#define NH 8
#define HD 64
#define C3 1536
#define QKLD 1024  // row length of qkT [n][o2], o2 in [0,1024): Q then K

typedef __hip_bfloat16 bf16;
typedef unsigned short ushort_t;

typedef __attribute__((ext_vector_type(8))) short bf16x8;
typedef __attribute__((ext_vector_type(8))) unsigned short ushortx8;
typedef __attribute__((ext_vector_type(4))) float floatx4;

__device__ __forceinline__ float b2f(bf16 h) { return __bfloat162float(h); }
__device__ __forceinline__ bf16 f2b(float f) { return __float2bfloat16(f); }
__device__ __forceinline__ ushort_t f2us(float f) {
    bf16 h = __float2bfloat16(f);
    return *(ushort_t*)&h;
}

// global_load_lds width=16: gsrc per-lane global addr; ldst wave-uniform LDS base,
// HW writes ldst + lane*16.
#define GLD16(gsrc, ldst)                                                        \
    __builtin_amdgcn_global_load_lds(                                            \
        (const __attribute__((address_space(1))) unsigned int*)(const void*)(gsrc), \
        (__attribute__((address_space(3))) unsigned int*)(void*)(ldst), 16, 0, 0)

// ---------------- GroupNorm, 1024-thread blocks.
// Blocks 0..255: one per (b,g), single global read, single Lt transpose pass (2 barriers).
// Blocks 256..511: weight f32->bf16 conversion, one 4096-float chunk each, single shot.
__global__ __launch_bounds__(1024, 1) void gn_kernel(const float* __restrict__ x,
                                                     const float* __restrict__ gamma,
                                                     const float* __restrict__ beta,
                                                     bf16* __restrict__ xnT,
                                                     const float* __restrict__ wqkv,
                                                     const float* __restrict__ wproj,
                                                     ushort_t* __restrict__ wqkvB,
                                                     ushort_t* __restrict__ wprojB) {
    int tid = threadIdx.x;
    if (blockIdx.x >= 256) {
        // 192 blocks -> wqkv (192*4096 = C3*CC), 64 blocks -> wproj (64*4096 = CC*CC)
        int wb = blockIdx.x - 256;
        const float* src;
        ushort_t* dst;
        int base;
        if (wb < 192) { src = wqkv; dst = wqkvB; base = wb * 4096; }
        else          { src = wproj; dst = wprojB; base = (wb - 192) * 4096; }
        int o = base + tid * 4;
        float4 f = *(const float4*)(src + o);
        ushort_t u[4] = {f2us(f.x), f2us(f.y), f2us(f.z), f2us(f.w)};
        *(uint2*)(dst + o) = *(uint2*)u;
        return;
    }

    const int GSZ = CPG * NN;  // 16384, contiguous per group
    int b = blockIdx.x >> 5;
    int g = blockIdx.x & 31;
    size_t base = ((size_t)b * CC + (size_t)g * CPG) * NN;

    int c_loc = tid >> 6;            // 0..15
    int nsp   = (tid & 63) * 16;     // n sub-span 0..1008
    const float* srcp = x + base + (size_t)c_loc * NN + nsp;

    float fv[16];
    *(float4*)(fv + 0)  = *(const float4*)(srcp + 0);
    *(float4*)(fv + 4)  = *(const float4*)(srcp + 4);
    *(float4*)(fv + 8)  = *(const float4*)(srcp + 8);
    *(float4*)(fv + 12) = *(const float4*)(srcp + 12);
    float s = 0.f, s2 = 0.f;
#pragma unroll
    for (int j = 0; j < 16; ++j) { float v = fv[j]; s += v; s2 += v * v; }

#pragma unroll
    for (int off = 32; off > 0; off >>= 1) {
        s  += __shfl_down(s, off, 64);
        s2 += __shfl_down(s2, off, 64);
    }
    __shared__ float rs[16], rs2[16], stat[2];
    __shared__ ushort_t Lt[16][1032];  // [c][n + 8 pad], 33 KB
    int wid = tid >> 6, lane = tid & 63;
    if (lane == 0) { rs[wid] = s; rs2[wid] = s2; }
    __syncthreads();
    if (tid == 0) {
        float ts = 0.f, ts2 = 0.f;
#pragma unroll
        for (int w = 0; w < 16; ++w) { ts += rs[w]; ts2 += rs2[w]; }
        float mean = ts * (1.f / GSZ);
        float var  = ts2 * (1.f / GSZ) - mean * mean;
        stat[0] = mean;
        stat[1] = rsqrtf(var + 1e-5f);
    }
    __syncthreads();
    float mean = stat[0], inv = stat[1];

    float ga = gamma[g * CPG + c_loc];
    float be = beta[g * CPG + c_loc];

    ushortx8 u0, u1;
#pragma unroll
    for (int j = 0; j < 8; ++j) {
        u0[j] = f2us((fv[j]     - mean) * inv * ga + be);
        u1[j] = f2us((fv[j + 8] - mean) * inv * ga + be);
    }
    *(ushortx8*)&Lt[c_loc][nsp]     = u0;
    *(ushortx8*)&Lt[c_loc][nsp + 8] = u1;
    __syncthreads();

    ushort_t o16[16];
#pragma unroll
    for (int c = 0; c < 16; ++c) o16[c] = Lt[c][tid];
    ushort_t* dst = (ushort_t*)xnT + ((size_t)b * NN + tid) * CC + g * CPG;
    *(uint4*)dst       = *(const uint4*)(o16);
    *(uint4*)(dst + 8) = *(const uint4*)(o16 + 8);
}

// ---------------- QKV GEMM: 128x128 tile, BK=64 single-buffered global_load_lds.
// (unchanged from round 12: 8 drain pairs, 32 MFMA each, 0-conflict swizzle)
__global__ __launch_bounds__(256) void qkv_gemm(const ushort_t* __restrict__ wB,
                                                const bf16* __restrict__ xnT,
                                                const float* __restrict__ bias,
                                                bf16* __restrict__ qkT,
                                                bf16* __restrict__ vN) {
    __shared__ ushort_t Wl[128 * 64];  // [o][k] 128B rows, 16 KB
    __shared__ ushort_t Xl[128 * 64];  // [n][k] 128B rows, 16 KB
    int b  = blockIdx.z;
    int o0 = blockIdx.y * 128;
    int n0 = blockIdx.x * 128;
    int tid = threadIdx.x;
    int wv = tid >> 6, l = tid & 63, ln = l & 15, qd = (l >> 4) & 3;
    int wm = wv >> 1, wn = wv & 1;

    // staging: wave wv stages rows [32wv, 32wv+32) per array, 4 GLD16 calls of 8 rows.
    int strow = wv * 32 + (l >> 3);          // call c adds 8
    int sgran = (l & 7) ^ (l >> 3);          // source granule pre-swizzle
    const ushort_t* wsrc = wB + (size_t)(o0 + strow) * CC + sgran * 8;
    const ushort_t* xsrc = (const ushort_t*)xnT + ((size_t)b * NN + n0 + strow) * CC + sgran * 8;

    floatx4 acc[4][4];
#pragma unroll
    for (int i = 0; i < 4; ++i)
#pragma unroll
        for (int j = 0; j < 4; ++j) acc[i][j] = (floatx4){0.f, 0.f, 0.f, 0.f};

    for (int k0 = 0; k0 < CC; k0 += 64) {
#pragma unroll
        for (int c = 0; c < 4; ++c) {
            GLD16(wsrc + k0 + (size_t)c * 8 * CC, &Wl[(wv * 32 + c * 8) * 64]);
            GLD16(xsrc + k0 + (size_t)c * 8 * CC, &Xl[(wv * 32 + c * 8) * 64]);
        }
        __syncthreads();   // drains vmcnt -> DMA complete
#pragma unroll
        for (int kk = 0; kk < 2; ++kk) {
            int qs = ((kk * 4 + qd) ^ (ln & 7)) * 8;
            bf16x8 af[4], bfr[4];
#pragma unroll
            for (int i = 0; i < 4; ++i)
                af[i] = *(const bf16x8*)&Wl[(wm * 64 + i * 16 + ln) * 64 + qs];
#pragma unroll
            for (int j = 0; j < 4; ++j)
                bfr[j] = *(const bf16x8*)&Xl[(wn * 64 + j * 16 + ln) * 64 + qs];
#pragma unroll
            for (int i = 0; i < 4; ++i)
#pragma unroll
                for (int j = 0; j < 4; ++j)
                    acc[i][j] = __builtin_amdgcn_mfma_f32_16x16x32_bf16(af[i], bfr[j], acc[i][j], 0, 0, 0);
        }
        __syncthreads();
    }

    if (o0 < 1024) {
#pragma unroll
        for (int i = 0; i < 4; ++i) {
            int ob = o0 + wm * 64 + i * 16 + qd * 4;
            float sc = (ob < 512) ? 0.18033688011112042f : 1.0f;  // 0.125 * log2(e)
#pragma unroll
            for (int j = 0; j < 4; ++j) {
                int n = n0 + wn * 64 + j * 16 + ln;
                ushort_t pk[4];
#pragma unroll
                for (int r = 0; r < 4; ++r)
                    pk[r] = f2us((acc[i][j][r] + bias[ob + r]) * sc);
                *(uint2*)((ushort_t*)qkT + ((size_t)b * NN + n) * QKLD + ob) = *(uint2*)pk;
            }
        }
    } else {
#pragma unroll
        for (int i = 0; i < 4; ++i) {
#pragma unroll
            for (int r = 0; r < 4; ++r) {
                int o = o0 + wm * 64 + i * 16 + qd * 4 + r;
                float bb = bias[o];
                size_t rb = ((size_t)b * CC + (o - 1024)) * NN + n0 + wn * 64 + ln;
#pragma unroll
                for (int j = 0; j < 4; ++j)
                    vN[rb + j * 16] = f2b(acc[i][j][r] + bb);
            }
        }
    }
}

// ---------------- Flash attention: one block per (h, 64-query tile, b) ----------------
// (round-10/12 version: 64 queries/block, 40960 B LDS, 4 blocks/CU, 0 conflicts)
__global__ __launch_bounds__(256, 4) void attn_kernel(const bf16* __restrict__ qkTp,
                                                      const bf16* __restrict__ vNp,
                                                      bf16* __restrict__ aoT) {
    __shared__ ushort_t Kt[2][64 * 64];   // [buf][key][ch]  (swizzled granules)
    __shared__ ushort_t Vn[2][64 * 64];   // [buf][ch][key]  (swizzled granules)
    __shared__ ushort_t Pw[4][16 * 64];   // per-wave [q][key] (swizzled granules)

    int h  = blockIdx.x;        // head (XCD affinity: blockid%8 == h)
    int qt = blockIdx.y;        // query tile 0..15
    int bi = blockIdx.z;
    int q0 = qt * 64;
    int tid = threadIdx.x;
    int wq = tid >> 6;          // wave id: owns queries wq*16..+15
    int l  = tid & 63;
    int ln = l & 15;
    int qd = (l >> 4) & 3;      // quad
    int l7 = ln & 7;
    int lb = ln >> 3;           // 0/1

    const ushort_t* qkT = (const ushort_t*)qkTp;
    const ushort_t* vN  = (const ushort_t*)vNp;

    const ushort_t* qsrc = qkT + ((size_t)bi * NN + q0 + wq * 16 + ln) * QKLD + h * HD + qd * 8;
    bf16x8 aq0 = *(const bf16x8*)(qsrc);
    bf16x8 aq1 = *(const bf16x8*)(qsrc + 32);

    bf16x8 ones;
#pragma unroll
    for (int j = 0; j < 8; ++j) ones[j] = (short)0x3F80;  // bf16 1.0

    floatx4 O[4];
#pragma unroll
    for (int t = 0; t < 4; ++t) O[t] = (floatx4){0.f, 0.f, 0.f, 0.f};
    floatx4 lsum = (floatx4){0.f, 0.f, 0.f, 0.f};

    ushort_t* Pme = &Pw[wq][0];

    int ksl0 = (qd ^ l7) * 8;
    int ksl1 = ((qd + 4) ^ l7) * 8;

    int srow = tid >> 2;            // 0..63
    int g1   = tid & 3;             // granules g1, g1+4
    int s7   = srow & 7;
    int ko1  = (g1 ^ s7) * 8;
    int ko2  = ((g1 + 4) ^ s7) * 8;
    const ushort_t* ks = qkT + ((size_t)bi * NN + srow) * QKLD + 512 + h * HD + g1 * 8;
    const ushort_t* vs = vN + ((size_t)bi * CC + h * HD + srow) * NN + g1 * 8;

    uint4 kr0 = *(const uint4*)(ks);
    uint4 kr1 = *(const uint4*)(ks + 32);
    uint4 vr0 = *(const uint4*)(vs);
    uint4 vr1 = *(const uint4*)(vs + 32);
    {
        ushort_t* kd = &Kt[0][srow * 64];
        *(uint4*)(kd + ko1) = kr0; *(uint4*)(kd + ko2) = kr1;
        ushort_t* vd = &Vn[0][srow * 64];
        *(uint4*)(vd + ko1) = vr0; *(uint4*)(vd + ko2) = vr1;
    }
    kr0 = *(const uint4*)(ks + (size_t)64 * QKLD);
    kr1 = *(const uint4*)(ks + (size_t)64 * QKLD + 32);
    vr0 = *(const uint4*)(vs + 64);
    vr1 = *(const uint4*)(vs + 64 + 32);
    __syncthreads();

    for (int it = 0; it < 16; ++it) {
        int cur = it & 1;
        const ushort_t* KtC = &Kt[cur][0];
        const ushort_t* VnC = &Vn[cur][0];
        if (it < 15) {
            ushort_t* kd = &Kt[cur ^ 1][srow * 64];
            *(uint4*)(kd + ko1) = kr0; *(uint4*)(kd + ko2) = kr1;
            ushort_t* vd = &Vn[cur ^ 1][srow * 64];
            *(uint4*)(vd + ko1) = vr0; *(uint4*)(vd + ko2) = vr1;
        }
        if (it < 14) {
            size_t mo = (size_t)(it + 2) * 64;
            kr0 = *(const uint4*)(ks + mo * QKLD);
            kr1 = *(const uint4*)(ks + mo * QKLD + 32);
            vr0 = *(const uint4*)(vs + mo);
            vr1 = *(const uint4*)(vs + mo + 32);
        }

        floatx4 S[4];
#pragma unroll
        for (int t = 0; t < 4; ++t) {
            const ushort_t* krow = KtC + (t * 16 + ln) * 64;
            bf16x8 b0 = *(const bf16x8*)(krow + ksl0);
            bf16x8 b1 = *(const bf16x8*)(krow + ksl1);
            floatx4 acc = (floatx4){0.f, 0.f, 0.f, 0.f};
            acc = __builtin_amdgcn_mfma_f32_16x16x32_bf16(aq0, b0, acc, 0, 0, 0);
            acc = __builtin_amdgcn_mfma_f32_16x16x32_bf16(aq1, b1, acc, 0, 0, 0);
            S[t] = acc;
        }

#pragma unroll
        for (int t = 0; t < 4; ++t) {
#pragma unroll
            for (int r = 0; r < 4; ++r) {
                float p = exp2f(S[t][r]);
                int qr = qd * 4 + r;
                Pme[qr * 64 + ((t * 2 + lb) ^ (qr & 7)) * 8 + l7] = f2us(p);
            }
        }
        bf16x8 pa0 = *(const bf16x8*)&Pme[ln * 64 + ksl0];
        bf16x8 pa1 = *(const bf16x8*)&Pme[ln * 64 + ksl1];

        lsum = __builtin_amdgcn_mfma_f32_16x16x32_bf16(pa0, ones, lsum, 0, 0, 0);
        lsum = __builtin_amdgcn_mfma_f32_16x16x32_bf16(pa1, ones, lsum, 0, 0, 0);

#pragma unroll
        for (int t = 0; t < 4; ++t) {
            const ushort_t* vrow = VnC + (t * 16 + ln) * 64;
            bf16x8 v0 = *(const bf16x8*)(vrow + ksl0);
            bf16x8 v1 = *(const bf16x8*)(vrow + ksl1);
            O[t] = __builtin_amdgcn_mfma_f32_16x16x32_bf16(pa0, v0, O[t], 0, 0, 0);
            O[t] = __builtin_amdgcn_mfma_f32_16x16x32_bf16(pa1, v1, O[t], 0, 0, 0);
        }
        if (it < 15) __syncthreads();
    }

    float inv[4];
#pragma unroll
    for (int r = 0; r < 4; ++r) inv[r] = 1.f / lsum[r];
#pragma unroll
    for (int t = 0; t < 4; ++t) {
#pragma unroll
        for (int r = 0; r < 4; ++r) {
            int n = q0 + wq * 16 + qd * 4 + r;
            ((ushort_t*)aoT)[((size_t)bi * NN + n) * CC + h * HD + t * 16 + ln] =
                f2us(O[t][r] * inv[r]);
        }
    }
}

// ---------------- Proj GEMM + bias + residual: 64x64 tile, BK=64 single-buffered.
// 8 drain pairs (was 16), 8 MFMA per pair (was 4); same bytes, 16 KB LDS.
// Staging/swizzle lifted verbatim from qkv: wave wv stages rows [16wv,16wv+16)
// per array, 2 GLD16 calls of 8 rows; slot g^(row&7); frag read ((kk*4+qd)^(ln&7)).
// Store epilogue byte-identical to round 10/12 (WRITE tripwire).
__global__ __launch_bounds__(256) void proj_gemm(const bf16* __restrict__ aoT,
                                                 const ushort_t* __restrict__ wB,
                                                 const float* __restrict__ bias,
                                                 const float* __restrict__ xres,
                                                 float* __restrict__ out) {
    __shared__ ushort_t Wl[64 * 64];   // [c_out][k] 128B rows, 8 KB
    __shared__ ushort_t Xl[64 * 64];   // [n][k] 128B rows, 8 KB
    int b  = blockIdx.z;
    int o0 = blockIdx.y * 64;
    int n0 = blockIdx.x * 64;
    int tid = threadIdx.x;
    int wv = tid >> 6, l = tid & 63, ln = l & 15, qd = (l >> 4) & 3;
    int wm = wv >> 1, wn = wv & 1;

    // staging: wave wv stages rows [16wv, 16wv+16) per array, 2 GLD16 calls of 8 rows.
    int strow = wv * 16 + (l >> 3);          // call c adds 8
    int sgran = (l & 7) ^ (l >> 3);          // source granule pre-swizzle
    const ushort_t* xsrc = (const ushort_t*)aoT + ((size_t)b * NN + n0 + strow) * CC + sgran * 8;
    const ushort_t* wsrc = wB + (size_t)(o0 + strow) * CC + sgran * 8;

    floatx4 acc[2][2];
#pragma unroll
    for (int i = 0; i < 2; ++i)
#pragma unroll
        for (int j = 0; j < 2; ++j) acc[i][j] = (floatx4){0.f, 0.f, 0.f, 0.f};

    for (int k0 = 0; k0 < CC; k0 += 64) {
#pragma unroll
        for (int c = 0; c < 2; ++c) {
            GLD16(wsrc + k0 + (size_t)c * 8 * CC, &Wl[(wv * 16 + c * 8) * 64]);
            GLD16(xsrc + k0 + (size_t)c * 8 * CC, &Xl[(wv * 16 + c * 8) * 64]);
        }
        __syncthreads();   // drains vmcnt -> DMA complete
#pragma unroll
        for (int kk = 0; kk < 2; ++kk) {
            int qs = ((kk * 4 + qd) ^ (ln & 7)) * 8;
            bf16x8 af[2], bfr[2];
#pragma unroll
            for (int i = 0; i < 2; ++i)
                af[i] = *(const bf16x8*)&Wl[(wm * 32 + i * 16 + ln) * 64 + qs];
#pragma unroll
            for (int j = 0; j < 2; ++j)
                bfr[j] = *(const bf16x8*)&Xl[(wn * 32 + j * 16 + ln) * 64 + qs];
#pragma unroll
            for (int i = 0; i < 2; ++i)
#pragma unroll
                for (int j = 0; j < 2; ++j)
                    acc[i][j] = __builtin_amdgcn_mfma_f32_16x16x32_bf16(af[i], bfr[j], acc[i][j], 0, 0, 0);
        }
        __syncthreads();
    }

#pragma unroll
    for (int i = 0; i < 2; ++i) {
#pragma unroll
        for (int r = 0; r < 4; ++r) {
            int o = o0 + wm * 32 + i * 16 + qd * 4 + r;
            float bb = bias[o];
            size_t rb = ((size_t)b * CC + o) * NN + n0 + wn * 32 + ln;
#pragma unroll
            for (int j = 0; j < 2; ++j)
                out[rb + j * 16] = acc[i][j][r] + bb + xres[rb + j * 16];
        }
    }
}

extern "C" void kernel_launch(void* const* d_in, const int* in_sizes, int n_in,
                              void* d_out, int out_size, void* d_ws, size_t ws_size,
                              hipStream_t stream) {
    const float* x      = (const float*)d_in[0];
    const float* gamma  = (const float*)d_in[1];
    const float* beta   = (const float*)d_in[2];
    const float* w_qkv  = (const float*)d_in[3];
    const float* b_qkv  = (const float*)d_in[4];
    const float* w_proj = (const float*)d_in[5];
    const float* b_proj = (const float*)d_in[6];
    float* out = (float*)d_out;

    // Workspace (bf16): xnT 8 MB | qkT 16 MB | vN 8 MB | wqkvB 1.5 MB | wprojB 0.5 MB.
    bf16* xnT = (bf16*)d_ws;                       // [b][n][c]
    bf16* qkT = xnT + (size_t)BB * CC * NN;        // [b][n][1024] (Q|K)
    bf16* vN  = qkT + (size_t)BB * NN * QKLD;      // [b][c][n]
    ushort_t* wqkvB  = (ushort_t*)(vN + (size_t)BB * CC * NN);  // [1536][512] bf16
    ushort_t* wprojB = wqkvB + (size_t)C3 * CC;                 // [512][512] bf16
    bf16* aoT = xnT;                               // [b][n][c], reuse

    gn_kernel<<<512, 1024, 0, stream>>>(x, gamma, beta, xnT,
                                        w_qkv, w_proj, wqkvB, wprojB);
    qkv_gemm<<<dim3(NN / 128, C3 / 128, BB), 256, 0, stream>>>(wqkvB, xnT, b_qkv, qkT, vN);
    attn_kernel<<<dim3(NH, NN / 64, BB), 256, 0, stream>>>(qkT, vN, aoT);
    proj_gemm<<<dim3(NN / 64, CC / 64, BB), 256, 0, stream>>>(aoT, wprojB, b_proj, x, out);
}

// Round 14
// 154.712 us; speedup vs baseline: 1.0006x; 1.0006x over previous
//
#include <hip/hip_runtime.h>
#include <hip/hip_bf16.h>

#define BB 8
#define CC 512
#define NN 1024   // H*W
#define NG 32
#define CPG 16
#define NH 8
#define HD 64
#define C3 1536
#define QKLD 1024  // row length of qkT [n][o2], o2 in [0,1024): Q then K

typedef __hip_bfloat16 bf16;
typedef unsigned short ushort_t;

typedef __attribute__((ext_vector_type(8))) short bf16x8;
typedef __attribute__((ext_vector_type(8))) unsigned short ushortx8;
typedef __attribute__((ext_vector_type(4))) float floatx4;

__device__ __forceinline__ float b2f(bf16 h) { return __bfloat162float(h); }
__device__ __forceinline__ bf16 f2b(float f) { return __float2bfloat16(f); }
__device__ __forceinline__ ushort_t f2us(float f) {
    bf16 h = __float2bfloat16(f);
    return *(ushort_t*)&h;
}

// global_load_lds width=16: gsrc per-lane global addr; ldst wave-uniform LDS base,
// HW writes ldst + lane*16.
#define GLD16(gsrc, ldst)                                                        \
    __builtin_amdgcn_global_load_lds(                                            \
        (const __attribute__((address_space(1))) unsigned int*)(const void*)(gsrc), \
        (__attribute__((address_space(3))) unsigned int*)(void*)(ldst), 16, 0, 0)

// ---------------- GroupNorm, 1024-thread blocks. (unchanged from round 13) ----------------
__global__ __launch_bounds__(1024, 1) void gn_kernel(const float* __restrict__ x,
                                                     const float* __restrict__ gamma,
                                                     const float* __restrict__ beta,
                                                     bf16* __restrict__ xnT,
                                                     const float* __restrict__ wqkv,
                                                     const float* __restrict__ wproj,
                                                     ushort_t* __restrict__ wqkvB,
                                                     ushort_t* __restrict__ wprojB) {
    int tid = threadIdx.x;
    if (blockIdx.x >= 256) {
        // 192 blocks -> wqkv (192*4096 = C3*CC), 64 blocks -> wproj (64*4096 = CC*CC)
        int wb = blockIdx.x - 256;
        const float* src;
        ushort_t* dst;
        int base;
        if (wb < 192) { src = wqkv; dst = wqkvB; base = wb * 4096; }
        else          { src = wproj; dst = wprojB; base = (wb - 192) * 4096; }
        int o = base + tid * 4;
        float4 f = *(const float4*)(src + o);
        ushort_t u[4] = {f2us(f.x), f2us(f.y), f2us(f.z), f2us(f.w)};
        *(uint2*)(dst + o) = *(uint2*)u;
        return;
    }

    const int GSZ = CPG * NN;  // 16384, contiguous per group
    int b = blockIdx.x >> 5;
    int g = blockIdx.x & 31;
    size_t base = ((size_t)b * CC + (size_t)g * CPG) * NN;

    int c_loc = tid >> 6;            // 0..15
    int nsp   = (tid & 63) * 16;     // n sub-span 0..1008
    const float* srcp = x + base + (size_t)c_loc * NN + nsp;

    float fv[16];
    *(float4*)(fv + 0)  = *(const float4*)(srcp + 0);
    *(float4*)(fv + 4)  = *(const float4*)(srcp + 4);
    *(float4*)(fv + 8)  = *(const float4*)(srcp + 8);
    *(float4*)(fv + 12) = *(const float4*)(srcp + 12);
    float s = 0.f, s2 = 0.f;
#pragma unroll
    for (int j = 0; j < 16; ++j) { float v = fv[j]; s += v; s2 += v * v; }

#pragma unroll
    for (int off = 32; off > 0; off >>= 1) {
        s  += __shfl_down(s, off, 64);
        s2 += __shfl_down(s2, off, 64);
    }
    __shared__ float rs[16], rs2[16], stat[2];
    __shared__ ushort_t Lt[16][1032];  // [c][n + 8 pad], 33 KB
    int wid = tid >> 6, lane = tid & 63;
    if (lane == 0) { rs[wid] = s; rs2[wid] = s2; }
    __syncthreads();
    if (tid == 0) {
        float ts = 0.f, ts2 = 0.f;
#pragma unroll
        for (int w = 0; w < 16; ++w) { ts += rs[w]; ts2 += rs2[w]; }
        float mean = ts * (1.f / GSZ);
        float var  = ts2 * (1.f / GSZ) - mean * mean;
        stat[0] = mean;
        stat[1] = rsqrtf(var + 1e-5f);
    }
    __syncthreads();
    float mean = stat[0], inv = stat[1];

    float ga = gamma[g * CPG + c_loc];
    float be = beta[g * CPG + c_loc];

    ushortx8 u0, u1;
#pragma unroll
    for (int j = 0; j < 8; ++j) {
        u0[j] = f2us((fv[j]     - mean) * inv * ga + be);
        u1[j] = f2us((fv[j + 8] - mean) * inv * ga + be);
    }
    *(ushortx8*)&Lt[c_loc][nsp]     = u0;
    *(ushortx8*)&Lt[c_loc][nsp + 8] = u1;
    __syncthreads();

    ushort_t o16[16];
#pragma unroll
    for (int c = 0; c < 16; ++c) o16[c] = Lt[c][tid];
    ushort_t* dst = (ushort_t*)xnT + ((size_t)b * NN + tid) * CC + g * CPG;
    *(uint4*)dst       = *(const uint4*)(o16);
    *(uint4*)(dst + 8) = *(const uint4*)(o16 + 8);
}

// ---------------- QKV GEMM: 128x128 tile, BK=32 double-buffered global_load_lds with
// T4 COUNTED-VMCNT pipeline: raw s_barrier (no drain) + s_waitcnt vmcnt(4) keeps the
// next tile's DMA in flight across the barrier. Ledger:
//   prologue: STAGE(0,b0) STAGE(1,b1)            [8 outstanding]
//   iter kt:  vmcnt(4) -> tile kt complete (kt+1 may fly); s_barrier (join: buffer full)
//             16 MFMA from buf[kt&1]; s_barrier (all reads done)
//             STAGE(kt+2 -> buf[kt&1])           [refill just-freed buffer]
//   tail:     kt=15 uses vmcnt(0) (bare vmcnt(4) would pass with tile 15 incomplete).
// Staging geometry + swizzle identical to round 9 (verified): lane l -> row l>>2,
// slot l&3, source granule (l&3)^((l>>2)&3); fragment read slot (qd^(ln&3)).
// MFMA loop and store epilogue byte-identical (WRITE/absmax tripwires).
__global__ __launch_bounds__(256) void qkv_gemm(const ushort_t* __restrict__ wB,
                                                const bf16* __restrict__ xnT,
                                                const float* __restrict__ bias,
                                                bf16* __restrict__ qkT,
                                                bf16* __restrict__ vN) {
    __shared__ ushort_t Wl[2][128 * 32];  // [buf][o][k] linear, 16 KB
    __shared__ ushort_t Xl[2][128 * 32];  // [buf][n][k] linear, 16 KB
    int b  = blockIdx.z;
    int o0 = blockIdx.y * 128;
    int n0 = blockIdx.x * 128;
    int tid = threadIdx.x;
    int wv = tid >> 6, l = tid & 63, ln = l & 15, qd = (l >> 4) & 3;
    int wm = wv >> 1, wn = wv & 1;

    int strow = wv * 32 + (l >> 2);          // call-0 row; call-1 adds 16
    int sgran = (l & 3) ^ ((l >> 2) & 3);    // source granule pre-swizzle
    const ushort_t* wsrc = wB + (size_t)(o0 + strow) * CC + sgran * 8;
    const ushort_t* xsrc = (const ushort_t*)xnT + ((size_t)b * NN + n0 + strow) * CC + sgran * 8;
    int lr0 = (wv * 32) * 32;
    int lr1 = (wv * 32 + 16) * 32;

#define QKV_STAGE(t, bf)                                         \
    do {                                                         \
        int ko_ = (t) * 32;                                      \
        GLD16(wsrc + ko_, &Wl[bf][lr0]);                         \
        GLD16(wsrc + ko_ + 16 * CC, &Wl[bf][lr1]);               \
        GLD16(xsrc + ko_, &Xl[bf][lr0]);                         \
        GLD16(xsrc + ko_ + 16 * CC, &Xl[bf][lr1]);               \
    } while (0)

    floatx4 acc[4][4];
#pragma unroll
    for (int i = 0; i < 4; ++i)
#pragma unroll
        for (int j = 0; j < 4; ++j) acc[i][j] = (floatx4){0.f, 0.f, 0.f, 0.f};

    int qs = (qd ^ (ln & 3)) * 8;            // swizzled fragment granule offset

    QKV_STAGE(0, 0);
    QKV_STAGE(1, 1);

    for (int kt = 0; kt < 16; ++kt) {
        if (kt < 15) { asm volatile("s_waitcnt vmcnt(4)" ::: "memory"); }
        else         { asm volatile("s_waitcnt vmcnt(0)" ::: "memory"); }
        __builtin_amdgcn_s_barrier();        // join: every wave's tile-kt DMA complete
        int cb = kt & 1;
        bf16x8 af[4], bfr[4];
#pragma unroll
        for (int i = 0; i < 4; ++i)
            af[i] = *(const bf16x8*)&Wl[cb][(wm * 64 + i * 16 + ln) * 32 + qs];
#pragma unroll
        for (int j = 0; j < 4; ++j)
            bfr[j] = *(const bf16x8*)&Xl[cb][(wn * 64 + j * 16 + ln) * 32 + qs];
#pragma unroll
        for (int i = 0; i < 4; ++i)
#pragma unroll
            for (int j = 0; j < 4; ++j)
                acc[i][j] = __builtin_amdgcn_mfma_f32_16x16x32_bf16(af[i], bfr[j], acc[i][j], 0, 0, 0);
        __builtin_amdgcn_s_barrier();        // all reads of buf[cb] done
        if (kt + 2 < 16) QKV_STAGE(kt + 2, cb);
    }
#undef QKV_STAGE

    if (o0 < 1024) {
#pragma unroll
        for (int i = 0; i < 4; ++i) {
            int ob = o0 + wm * 64 + i * 16 + qd * 4;
            float sc = (ob < 512) ? 0.18033688011112042f : 1.0f;  // 0.125 * log2(e)
#pragma unroll
            for (int j = 0; j < 4; ++j) {
                int n = n0 + wn * 64 + j * 16 + ln;
                ushort_t pk[4];
#pragma unroll
                for (int r = 0; r < 4; ++r)
                    pk[r] = f2us((acc[i][j][r] + bias[ob + r]) * sc);
                *(uint2*)((ushort_t*)qkT + ((size_t)b * NN + n) * QKLD + ob) = *(uint2*)pk;
            }
        }
    } else {
#pragma unroll
        for (int i = 0; i < 4; ++i) {
#pragma unroll
            for (int r = 0; r < 4; ++r) {
                int o = o0 + wm * 64 + i * 16 + qd * 4 + r;
                float bb = bias[o];
                size_t rb = ((size_t)b * CC + (o - 1024)) * NN + n0 + wn * 64 + ln;
#pragma unroll
                for (int j = 0; j < 4; ++j)
                    vN[rb + j * 16] = f2b(acc[i][j][r] + bb);
            }
        }
    }
}

// ---------------- Flash attention: one block per (h, 64-query tile, b) ----------------
// (round-10/12/13 version: 64 queries/block, 40960 B LDS, 4 blocks/CU, 0 conflicts)
__global__ __launch_bounds__(256, 4) void attn_kernel(const bf16* __restrict__ qkTp,
                                                      const bf16* __restrict__ vNp,
                                                      bf16* __restrict__ aoT) {
    __shared__ ushort_t Kt[2][64 * 64];   // [buf][key][ch]  (swizzled granules)
    __shared__ ushort_t Vn[2][64 * 64];   // [buf][ch][key]  (swizzled granules)
    __shared__ ushort_t Pw[4][16 * 64];   // per-wave [q][key] (swizzled granules)

    int h  = blockIdx.x;        // head (XCD affinity: blockid%8 == h)
    int qt = blockIdx.y;        // query tile 0..15
    int bi = blockIdx.z;
    int q0 = qt * 64;
    int tid = threadIdx.x;
    int wq = tid >> 6;          // wave id: owns queries wq*16..+15
    int l  = tid & 63;
    int ln = l & 15;
    int qd = (l >> 4) & 3;      // quad
    int l7 = ln & 7;
    int lb = ln >> 3;           // 0/1

    const ushort_t* qkT = (const ushort_t*)qkTp;
    const ushort_t* vN  = (const ushort_t*)vNp;

    const ushort_t* qsrc = qkT + ((size_t)bi * NN + q0 + wq * 16 + ln) * QKLD + h * HD + qd * 8;
    bf16x8 aq0 = *(const bf16x8*)(qsrc);
    bf16x8 aq1 = *(const bf16x8*)(qsrc + 32);

    bf16x8 ones;
#pragma unroll
    for (int j = 0; j < 8; ++j) ones[j] = (short)0x3F80;  // bf16 1.0

    floatx4 O[4];
#pragma unroll
    for (int t = 0; t < 4; ++t) O[t] = (floatx4){0.f, 0.f, 0.f, 0.f};
    floatx4 lsum = (floatx4){0.f, 0.f, 0.f, 0.f};

    ushort_t* Pme = &Pw[wq][0];

    int ksl0 = (qd ^ l7) * 8;
    int ksl1 = ((qd + 4) ^ l7) * 8;

    int srow = tid >> 2;            // 0..63
    int g1   = tid & 3;             // granules g1, g1+4
    int s7   = srow & 7;
    int ko1  = (g1 ^ s7) * 8;
    int ko2  = ((g1 + 4) ^ s7) * 8;
    const ushort_t* ks = qkT + ((size_t)bi * NN + srow) * QKLD + 512 + h * HD + g1 * 8;
    const ushort_t* vs = vN + ((size_t)bi * CC + h * HD + srow) * NN + g1 * 8;

    uint4 kr0 = *(const uint4*)(ks);
    uint4 kr1 = *(const uint4*)(ks + 32);
    uint4 vr0 = *(const uint4*)(vs);
    uint4 vr1 = *(const uint4*)(vs + 32);
    {
        ushort_t* kd = &Kt[0][srow * 64];
        *(uint4*)(kd + ko1) = kr0; *(uint4*)(kd + ko2) = kr1;
        ushort_t* vd = &Vn[0][srow * 64];
        *(uint4*)(vd + ko1) = vr0; *(uint4*)(vd + ko2) = vr1;
    }
    kr0 = *(const uint4*)(ks + (size_t)64 * QKLD);
    kr1 = *(const uint4*)(ks + (size_t)64 * QKLD + 32);
    vr0 = *(const uint4*)(vs + 64);
    vr1 = *(const uint4*)(vs + 64 + 32);
    __syncthreads();

    for (int it = 0; it < 16; ++it) {
        int cur = it & 1;
        const ushort_t* KtC = &Kt[cur][0];
        const ushort_t* VnC = &Vn[cur][0];
        if (it < 15) {
            ushort_t* kd = &Kt[cur ^ 1][srow * 64];
            *(uint4*)(kd + ko1) = kr0; *(uint4*)(kd + ko2) = kr1;
            ushort_t* vd = &Vn[cur ^ 1][srow * 64];
            *(uint4*)(vd + ko1) = vr0; *(uint4*)(vd + ko2) = vr1;
        }
        if (it < 14) {
            size_t mo = (size_t)(it + 2) * 64;
            kr0 = *(const uint4*)(ks + mo * QKLD);
            kr1 = *(const uint4*)(ks + mo * QKLD + 32);
            vr0 = *(const uint4*)(vs + mo);
            vr1 = *(const uint4*)(vs + mo + 32);
        }

        floatx4 S[4];
#pragma unroll
        for (int t = 0; t < 4; ++t) {
            const ushort_t* krow = KtC + (t * 16 + ln) * 64;
            bf16x8 b0 = *(const bf16x8*)(krow + ksl0);
            bf16x8 b1 = *(const bf16x8*)(krow + ksl1);
            floatx4 acc = (floatx4){0.f, 0.f, 0.f, 0.f};
            acc = __builtin_amdgcn_mfma_f32_16x16x32_bf16(aq0, b0, acc, 0, 0, 0);
            acc = __builtin_amdgcn_mfma_f32_16x16x32_bf16(aq1, b1, acc, 0, 0, 0);
            S[t] = acc;
        }

#pragma unroll
        for (int t = 0; t < 4; ++t) {
#pragma unroll
            for (int r = 0; r < 4; ++r) {
                float p = exp2f(S[t][r]);
                int qr = qd * 4 + r;
                Pme[qr * 64 + ((t * 2 + lb) ^ (qr & 7)) * 8 + l7] = f2us(p);
            }
        }
        bf16x8 pa0 = *(const bf16x8*)&Pme[ln * 64 + ksl0];
        bf16x8 pa1 = *(const bf16x8*)&Pme[ln * 64 + ksl1];

        lsum = __builtin_amdgcn_mfma_f32_16x16x32_bf16(pa0, ones, lsum, 0, 0, 0);
        lsum = __builtin_amdgcn_mfma_f32_16x16x32_bf16(pa1, ones, lsum, 0, 0, 0);

#pragma unroll
        for (int t = 0; t < 4; ++t) {
            const ushort_t* vrow = VnC + (t * 16 + ln) * 64;
            bf16x8 v0 = *(const bf16x8*)(vrow + ksl0);
            bf16x8 v1 = *(const bf16x8*)(vrow + ksl1);
            O[t] = __builtin_amdgcn_mfma_f32_16x16x32_bf16(pa0, v0, O[t], 0, 0, 0);
            O[t] = __builtin_amdgcn_mfma_f32_16x16x32_bf16(pa1, v1, O[t], 0, 0, 0);
        }
        if (it < 15) __syncthreads();
    }

    float inv[4];
#pragma unroll
    for (int r = 0; r < 4; ++r) inv[r] = 1.f / lsum[r];
#pragma unroll
    for (int t = 0; t < 4; ++t) {
#pragma unroll
        for (int r = 0; r < 4; ++r) {
            int n = q0 + wq * 16 + qd * 4 + r;
            ((ushort_t*)aoT)[((size_t)bi * NN + n) * CC + h * HD + t * 16 + ln] =
                f2us(O[t][r] * inv[r]);
        }
    }
}

// ---------------- Proj GEMM + bias + residual: 64x64 tile, BK=64 single-buffered.
// (unchanged from round 13)
__global__ __launch_bounds__(256) void proj_gemm(const bf16* __restrict__ aoT,
                                                 const ushort_t* __restrict__ wB,
                                                 const float* __restrict__ bias,
                                                 const float* __restrict__ xres,
                                                 float* __restrict__ out) {
    __shared__ ushort_t Wl[64 * 64];   // [c_out][k] 128B rows, 8 KB
    __shared__ ushort_t Xl[64 * 64];   // [n][k] 128B rows, 8 KB
    int b  = blockIdx.z;
    int o0 = blockIdx.y * 64;
    int n0 = blockIdx.x * 64;
    int tid = threadIdx.x;
    int wv = tid >> 6, l = tid & 63, ln = l & 15, qd = (l >> 4) & 3;
    int wm = wv >> 1, wn = wv & 1;

    // staging: wave wv stages rows [16wv, 16wv+16) per array, 2 GLD16 calls of 8 rows.
    int strow = wv * 16 + (l >> 3);          // call c adds 8
    int sgran = (l & 7) ^ (l >> 3);          // source granule pre-swizzle
    const ushort_t* xsrc = (const ushort_t*)aoT + ((size_t)b * NN + n0 + strow) * CC + sgran * 8;
    const ushort_t* wsrc = wB + (size_t)(o0 + strow) * CC + sgran * 8;

    floatx4 acc[2][2];
#pragma unroll
    for (int i = 0; i < 2; ++i)
#pragma unroll
        for (int j = 0; j < 2; ++j) acc[i][j] = (floatx4){0.f, 0.f, 0.f, 0.f};

    for (int k0 = 0; k0 < CC; k0 += 64) {
#pragma unroll
        for (int c = 0; c < 2; ++c) {
            GLD16(wsrc + k0 + (size_t)c * 8 * CC, &Wl[(wv * 16 + c * 8) * 64]);
            GLD16(xsrc + k0 + (size_t)c * 8 * CC, &Xl[(wv * 16 + c * 8) * 64]);
        }
        __syncthreads();   // drains vmcnt -> DMA complete
#pragma unroll
        for (int kk = 0; kk < 2; ++kk) {
            int qs = ((kk * 4 + qd) ^ (ln & 7)) * 8;
            bf16x8 af[2], bfr[2];
#pragma unroll
            for (int i = 0; i < 2; ++i)
                af[i] = *(const bf16x8*)&Wl[(wm * 32 + i * 16 + ln) * 64 + qs];
#pragma unroll
            for (int j = 0; j < 2; ++j)
                bfr[j] = *(const bf16x8*)&Xl[(wn * 32 + j * 16 + ln) * 64 + qs];
#pragma unroll
            for (int i = 0; i < 2; ++i)
#pragma unroll
                for (int j = 0; j < 2; ++j)
                    acc[i][j] = __builtin_amdgcn_mfma_f32_16x16x32_bf16(af[i], bfr[j], acc[i][j], 0, 0, 0);
        }
        __syncthreads();
    }

#pragma unroll
    for (int i = 0; i < 2; ++i) {
#pragma unroll
        for (int r = 0; r < 4; ++r) {
            int o = o0 + wm * 32 + i * 16 + qd * 4 + r;
            float bb = bias[o];
            size_t rb = ((size_t)b * CC + o) * NN + n0 + wn * 32 + ln;
#pragma unroll
            for (int j = 0; j < 2; ++j)
                out[rb + j * 16] = acc[i][j][r] + bb + xres[rb + j * 16];
        }
    }
}

extern "C" void kernel_launch(void* const* d_in, const int* in_sizes, int n_in,
                              void* d_out, int out_size, void* d_ws, size_t ws_size,
                              hipStream_t stream) {
    const float* x      = (const float*)d_in[0];
    const float* gamma  = (const float*)d_in[1];
    const float* beta   = (const float*)d_in[2];
    const float* w_qkv  = (const float*)d_in[3];
    const float* b_qkv  = (const float*)d_in[4];
    const float* w_proj = (const float*)d_in[5];
    const float* b_proj = (const float*)d_in[6];
    float* out = (float*)d_out;

    // Workspace (bf16): xnT 8 MB | qkT 16 MB | vN 8 MB | wqkvB 1.5 MB | wprojB 0.5 MB.
    bf16* xnT = (bf16*)d_ws;                       // [b][n][c]
    bf16* qkT = xnT + (size_t)BB * CC * NN;        // [b][n][1024] (Q|K)
    bf16* vN  = qkT + (size_t)BB * NN * QKLD;      // [b][c][n]
    ushort_t* wqkvB  = (ushort_t*)(vN + (size_t)BB * CC * NN);  // [1536][512] bf16
    ushort_t* wprojB = wqkvB + (size_t)C3 * CC;                 // [512][512] bf16
    bf16* aoT = xnT;                               // [b][n][c], reuse

    gn_kernel<<<512, 1024, 0, stream>>>(x, gamma, beta, xnT,
                                        w_qkv, w_proj, wqkvB, wprojB);
    qkv_gemm<<<dim3(NN / 128, C3 / 128, BB), 256, 0, stream>>>(wqkvB, xnT, b_qkv, qkT, vN);
    attn_kernel<<<dim3(NH, NN / 64, BB), 256, 0, stream>>>(qkT, vN, aoT);
    proj_gemm<<<dim3(NN / 64, CC / 64, BB), 256, 0, stream>>>(aoT, wprojB, b_proj, x, out);
}

// Round 15
// 152.835 us; speedup vs baseline: 1.0129x; 1.0123x over previous
//
#include <hip/hip_runtime.h>
#include <hip/hip_bf16.h>

#define BB 8
#define CC 512
#define NN 1024   // H*W
#define NG 32
#define CPG 16
#define NH 8
#define HD 64
#define C3 1536
#define QKLD 1024  // row length of qkT [n][o2], o2 in [0,1024): Q then K

typedef __hip_bfloat16 bf16;
typedef unsigned short ushort_t;

typedef __attribute__((ext_vector_type(8))) short bf16x8;
typedef __attribute__((ext_vector_type(8))) unsigned short ushortx8;
typedef __attribute__((ext_vector_type(4))) float floatx4;

__device__ __forceinline__ float b2f(bf16 h) { return __bfloat162float(h); }
__device__ __forceinline__ bf16 f2b(float f) { return __float2bfloat16(f); }
__device__ __forceinline__ ushort_t f2us(float f) {
    bf16 h = __float2bfloat16(f);
    return *(ushort_t*)&h;
}

#if __has_builtin(__builtin_amdgcn_exp2f)
#define EXP2F(x) __builtin_amdgcn_exp2f(x)
#else
#define EXP2F(x) exp2f(x)
#endif

// global_load_lds width=16: gsrc per-lane global addr; ldst wave-uniform LDS base,
// HW writes ldst + lane*16.
#define GLD16(gsrc, ldst)                                                        \
    __builtin_amdgcn_global_load_lds(                                            \
        (const __attribute__((address_space(1))) unsigned int*)(const void*)(gsrc), \
        (__attribute__((address_space(3))) unsigned int*)(void*)(ldst), 16, 0, 0)

// ---------------- GroupNorm, 1024-thread blocks. (unchanged from round 13/14) ----------------
__global__ __launch_bounds__(1024, 1) void gn_kernel(const float* __restrict__ x,
                                                     const float* __restrict__ gamma,
                                                     const float* __restrict__ beta,
                                                     bf16* __restrict__ xnT,
                                                     const float* __restrict__ wqkv,
                                                     const float* __restrict__ wproj,
                                                     ushort_t* __restrict__ wqkvB,
                                                     ushort_t* __restrict__ wprojB) {
    int tid = threadIdx.x;
    if (blockIdx.x >= 256) {
        // 192 blocks -> wqkv (192*4096 = C3*CC), 64 blocks -> wproj (64*4096 = CC*CC)
        int wb = blockIdx.x - 256;
        const float* src;
        ushort_t* dst;
        int base;
        if (wb < 192) { src = wqkv; dst = wqkvB; base = wb * 4096; }
        else          { src = wproj; dst = wprojB; base = (wb - 192) * 4096; }
        int o = base + tid * 4;
        float4 f = *(const float4*)(src + o);
        ushort_t u[4] = {f2us(f.x), f2us(f.y), f2us(f.z), f2us(f.w)};
        *(uint2*)(dst + o) = *(uint2*)u;
        return;
    }

    const int GSZ = CPG * NN;  // 16384, contiguous per group
    int b = blockIdx.x >> 5;
    int g = blockIdx.x & 31;
    size_t base = ((size_t)b * CC + (size_t)g * CPG) * NN;

    int c_loc = tid >> 6;            // 0..15
    int nsp   = (tid & 63) * 16;     // n sub-span 0..1008
    const float* srcp = x + base + (size_t)c_loc * NN + nsp;

    float fv[16];
    *(float4*)(fv + 0)  = *(const float4*)(srcp + 0);
    *(float4*)(fv + 4)  = *(const float4*)(srcp + 4);
    *(float4*)(fv + 8)  = *(const float4*)(srcp + 8);
    *(float4*)(fv + 12) = *(const float4*)(srcp + 12);
    float s = 0.f, s2 = 0.f;
#pragma unroll
    for (int j = 0; j < 16; ++j) { float v = fv[j]; s += v; s2 += v * v; }

#pragma unroll
    for (int off = 32; off > 0; off >>= 1) {
        s  += __shfl_down(s, off, 64);
        s2 += __shfl_down(s2, off, 64);
    }
    __shared__ float rs[16], rs2[16], stat[2];
    __shared__ ushort_t Lt[16][1032];  // [c][n + 8 pad], 33 KB
    int wid = tid >> 6, lane = tid & 63;
    if (lane == 0) { rs[wid] = s; rs2[wid] = s2; }
    __syncthreads();
    if (tid == 0) {
        float ts = 0.f, ts2 = 0.f;
#pragma unroll
        for (int w = 0; w < 16; ++w) { ts += rs[w]; ts2 += rs2[w]; }
        float mean = ts * (1.f / GSZ);
        float var  = ts2 * (1.f / GSZ) - mean * mean;
        stat[0] = mean;
        stat[1] = rsqrtf(var + 1e-5f);
    }
    __syncthreads();
    float mean = stat[0], inv = stat[1];

    float ga = gamma[g * CPG + c_loc];
    float be = beta[g * CPG + c_loc];

    ushortx8 u0, u1;
#pragma unroll
    for (int j = 0; j < 8; ++j) {
        u0[j] = f2us((fv[j]     - mean) * inv * ga + be);
        u1[j] = f2us((fv[j + 8] - mean) * inv * ga + be);
    }
    *(ushortx8*)&Lt[c_loc][nsp]     = u0;
    *(ushortx8*)&Lt[c_loc][nsp + 8] = u1;
    __syncthreads();

    ushort_t o16[16];
#pragma unroll
    for (int c = 0; c < 16; ++c) o16[c] = Lt[c][tid];
    ushort_t* dst = (ushort_t*)xnT + ((size_t)b * NN + tid) * CC + g * CPG;
    *(uint4*)dst       = *(const uint4*)(o16);
    *(uint4*)(dst + 8) = *(const uint4*)(o16 + 8);
}

// ---------------- QKV GEMM: 128x128 tile, BK=32 double-buffered global_load_lds with
// T4 counted-vmcnt pipeline (round 14) + T5 s_setprio around the MFMA cluster.
__global__ __launch_bounds__(256) void qkv_gemm(const ushort_t* __restrict__ wB,
                                                const bf16* __restrict__ xnT,
                                                const float* __restrict__ bias,
                                                bf16* __restrict__ qkT,
                                                bf16* __restrict__ vN) {
    __shared__ ushort_t Wl[2][128 * 32];  // [buf][o][k] linear, 16 KB
    __shared__ ushort_t Xl[2][128 * 32];  // [buf][n][k] linear, 16 KB
    int b  = blockIdx.z;
    int o0 = blockIdx.y * 128;
    int n0 = blockIdx.x * 128;
    int tid = threadIdx.x;
    int wv = tid >> 6, l = tid & 63, ln = l & 15, qd = (l >> 4) & 3;
    int wm = wv >> 1, wn = wv & 1;

    int strow = wv * 32 + (l >> 2);          // call-0 row; call-1 adds 16
    int sgran = (l & 3) ^ ((l >> 2) & 3);    // source granule pre-swizzle
    const ushort_t* wsrc = wB + (size_t)(o0 + strow) * CC + sgran * 8;
    const ushort_t* xsrc = (const ushort_t*)xnT + ((size_t)b * NN + n0 + strow) * CC + sgran * 8;
    int lr0 = (wv * 32) * 32;
    int lr1 = (wv * 32 + 16) * 32;

#define QKV_STAGE(t, bf)                                         \
    do {                                                         \
        int ko_ = (t) * 32;                                      \
        GLD16(wsrc + ko_, &Wl[bf][lr0]);                         \
        GLD16(wsrc + ko_ + 16 * CC, &Wl[bf][lr1]);               \
        GLD16(xsrc + ko_, &Xl[bf][lr0]);                         \
        GLD16(xsrc + ko_ + 16 * CC, &Xl[bf][lr1]);               \
    } while (0)

    floatx4 acc[4][4];
#pragma unroll
    for (int i = 0; i < 4; ++i)
#pragma unroll
        for (int j = 0; j < 4; ++j) acc[i][j] = (floatx4){0.f, 0.f, 0.f, 0.f};

    int qs = (qd ^ (ln & 3)) * 8;            // swizzled fragment granule offset

    QKV_STAGE(0, 0);
    QKV_STAGE(1, 1);

    for (int kt = 0; kt < 16; ++kt) {
        if (kt < 15) { asm volatile("s_waitcnt vmcnt(4)" ::: "memory"); }
        else         { asm volatile("s_waitcnt vmcnt(0)" ::: "memory"); }
        __builtin_amdgcn_s_barrier();        // join: every wave's tile-kt DMA complete
        int cb = kt & 1;
        bf16x8 af[4], bfr[4];
#pragma unroll
        for (int i = 0; i < 4; ++i)
            af[i] = *(const bf16x8*)&Wl[cb][(wm * 64 + i * 16 + ln) * 32 + qs];
#pragma unroll
        for (int j = 0; j < 4; ++j)
            bfr[j] = *(const bf16x8*)&Xl[cb][(wn * 64 + j * 16 + ln) * 32 + qs];
        __builtin_amdgcn_s_setprio(1);
#pragma unroll
        for (int i = 0; i < 4; ++i)
#pragma unroll
            for (int j = 0; j < 4; ++j)
                acc[i][j] = __builtin_amdgcn_mfma_f32_16x16x32_bf16(af[i], bfr[j], acc[i][j], 0, 0, 0);
        __builtin_amdgcn_s_setprio(0);
        __builtin_amdgcn_s_barrier();        // all reads of buf[cb] done
        if (kt + 2 < 16) QKV_STAGE(kt + 2, cb);
    }
#undef QKV_STAGE

    if (o0 < 1024) {
#pragma unroll
        for (int i = 0; i < 4; ++i) {
            int ob = o0 + wm * 64 + i * 16 + qd * 4;
            float sc = (ob < 512) ? 0.18033688011112042f : 1.0f;  // 0.125 * log2(e)
#pragma unroll
            for (int j = 0; j < 4; ++j) {
                int n = n0 + wn * 64 + j * 16 + ln;
                ushort_t pk[4];
#pragma unroll
                for (int r = 0; r < 4; ++r)
                    pk[r] = f2us((acc[i][j][r] + bias[ob + r]) * sc);
                *(uint2*)((ushort_t*)qkT + ((size_t)b * NN + n) * QKLD + ob) = *(uint2*)pk;
            }
        }
    } else {
#pragma unroll
        for (int i = 0; i < 4; ++i) {
#pragma unroll
            for (int r = 0; r < 4; ++r) {
                int o = o0 + wm * 64 + i * 16 + qd * 4 + r;
                float bb = bias[o];
                size_t rb = ((size_t)b * CC + (o - 1024)) * NN + n0 + wn * 64 + ln;
#pragma unroll
                for (int j = 0; j < 4; ++j)
                    vN[rb + j * 16] = f2b(acc[i][j][r] + bb);
            }
        }
    }
}

// ---------------- Flash attention: one block per (h, 64-query tile, b) ----------------
// Round-10/12/13/14 structure + T5 s_setprio around MFMA clusters (4 independent
// blocks/CU at different KV-steps -> scheduler arbitration has something to bias)
// + raw v_exp_f32 via __builtin_amdgcn_exp2f.
__global__ __launch_bounds__(256, 4) void attn_kernel(const bf16* __restrict__ qkTp,
                                                      const bf16* __restrict__ vNp,
                                                      bf16* __restrict__ aoT) {
    __shared__ ushort_t Kt[2][64 * 64];   // [buf][key][ch]  (swizzled granules)
    __shared__ ushort_t Vn[2][64 * 64];   // [buf][ch][key]  (swizzled granules)
    __shared__ ushort_t Pw[4][16 * 64];   // per-wave [q][key] (swizzled granules)

    int h  = blockIdx.x;        // head (XCD affinity: blockid%8 == h)
    int qt = blockIdx.y;        // query tile 0..15
    int bi = blockIdx.z;
    int q0 = qt * 64;
    int tid = threadIdx.x;
    int wq = tid >> 6;          // wave id: owns queries wq*16..+15
    int l  = tid & 63;
    int ln = l & 15;
    int qd = (l >> 4) & 3;      // quad
    int l7 = ln & 7;
    int lb = ln >> 3;           // 0/1

    const ushort_t* qkT = (const ushort_t*)qkTp;
    const ushort_t* vN  = (const ushort_t*)vNp;

    const ushort_t* qsrc = qkT + ((size_t)bi * NN + q0 + wq * 16 + ln) * QKLD + h * HD + qd * 8;
    bf16x8 aq0 = *(const bf16x8*)(qsrc);
    bf16x8 aq1 = *(const bf16x8*)(qsrc + 32);

    bf16x8 ones;
#pragma unroll
    for (int j = 0; j < 8; ++j) ones[j] = (short)0x3F80;  // bf16 1.0

    floatx4 O[4];
#pragma unroll
    for (int t = 0; t < 4; ++t) O[t] = (floatx4){0.f, 0.f, 0.f, 0.f};
    floatx4 lsum = (floatx4){0.f, 0.f, 0.f, 0.f};

    ushort_t* Pme = &Pw[wq][0];

    int ksl0 = (qd ^ l7) * 8;
    int ksl1 = ((qd + 4) ^ l7) * 8;

    int srow = tid >> 2;            // 0..63
    int g1   = tid & 3;             // granules g1, g1+4
    int s7   = srow & 7;
    int ko1  = (g1 ^ s7) * 8;
    int ko2  = ((g1 + 4) ^ s7) * 8;
    const ushort_t* ks = qkT + ((size_t)bi * NN + srow) * QKLD + 512 + h * HD + g1 * 8;
    const ushort_t* vs = vN + ((size_t)bi * CC + h * HD + srow) * NN + g1 * 8;

    uint4 kr0 = *(const uint4*)(ks);
    uint4 kr1 = *(const uint4*)(ks + 32);
    uint4 vr0 = *(const uint4*)(vs);
    uint4 vr1 = *(const uint4*)(vs + 32);
    {
        ushort_t* kd = &Kt[0][srow * 64];
        *(uint4*)(kd + ko1) = kr0; *(uint4*)(kd + ko2) = kr1;
        ushort_t* vd = &Vn[0][srow * 64];
        *(uint4*)(vd + ko1) = vr0; *(uint4*)(vd + ko2) = vr1;
    }
    kr0 = *(const uint4*)(ks + (size_t)64 * QKLD);
    kr1 = *(const uint4*)(ks + (size_t)64 * QKLD + 32);
    vr0 = *(const uint4*)(vs + 64);
    vr1 = *(const uint4*)(vs + 64 + 32);
    __syncthreads();

    for (int it = 0; it < 16; ++it) {
        int cur = it & 1;
        const ushort_t* KtC = &Kt[cur][0];
        const ushort_t* VnC = &Vn[cur][0];
        if (it < 15) {
            ushort_t* kd = &Kt[cur ^ 1][srow * 64];
            *(uint4*)(kd + ko1) = kr0; *(uint4*)(kd + ko2) = kr1;
            ushort_t* vd = &Vn[cur ^ 1][srow * 64];
            *(uint4*)(vd + ko1) = vr0; *(uint4*)(vd + ko2) = vr1;
        }
        if (it < 14) {
            size_t mo = (size_t)(it + 2) * 64;
            kr0 = *(const uint4*)(ks + mo * QKLD);
            kr1 = *(const uint4*)(ks + mo * QKLD + 32);
            vr0 = *(const uint4*)(vs + mo);
            vr1 = *(const uint4*)(vs + mo + 32);
        }

        floatx4 S[4];
        __builtin_amdgcn_s_setprio(1);
#pragma unroll
        for (int t = 0; t < 4; ++t) {
            const ushort_t* krow = KtC + (t * 16 + ln) * 64;
            bf16x8 b0 = *(const bf16x8*)(krow + ksl0);
            bf16x8 b1 = *(const bf16x8*)(krow + ksl1);
            floatx4 acc = (floatx4){0.f, 0.f, 0.f, 0.f};
            acc = __builtin_amdgcn_mfma_f32_16x16x32_bf16(aq0, b0, acc, 0, 0, 0);
            acc = __builtin_amdgcn_mfma_f32_16x16x32_bf16(aq1, b1, acc, 0, 0, 0);
            S[t] = acc;
        }
        __builtin_amdgcn_s_setprio(0);

#pragma unroll
        for (int t = 0; t < 4; ++t) {
#pragma unroll
            for (int r = 0; r < 4; ++r) {
                float p = EXP2F(S[t][r]);
                int qr = qd * 4 + r;
                Pme[qr * 64 + ((t * 2 + lb) ^ (qr & 7)) * 8 + l7] = f2us(p);
            }
        }
        bf16x8 pa0 = *(const bf16x8*)&Pme[ln * 64 + ksl0];
        bf16x8 pa1 = *(const bf16x8*)&Pme[ln * 64 + ksl1];

        __builtin_amdgcn_s_setprio(1);
        lsum = __builtin_amdgcn_mfma_f32_16x16x32_bf16(pa0, ones, lsum, 0, 0, 0);
        lsum = __builtin_amdgcn_mfma_f32_16x16x32_bf16(pa1, ones, lsum, 0, 0, 0);

#pragma unroll
        for (int t = 0; t < 4; ++t) {
            const ushort_t* vrow = VnC + (t * 16 + ln) * 64;
            bf16x8 v0 = *(const bf16x8*)(vrow + ksl0);
            bf16x8 v1 = *(const bf16x8*)(vrow + ksl1);
            O[t] = __builtin_amdgcn_mfma_f32_16x16x32_bf16(pa0, v0, O[t], 0, 0, 0);
            O[t] = __builtin_amdgcn_mfma_f32_16x16x32_bf16(pa1, v1, O[t], 0, 0, 0);
        }
        __builtin_amdgcn_s_setprio(0);
        if (it < 15) __syncthreads();
    }

    float inv[4];
#pragma unroll
    for (int r = 0; r < 4; ++r) inv[r] = 1.f / lsum[r];
#pragma unroll
    for (int t = 0; t < 4; ++t) {
#pragma unroll
        for (int r = 0; r < 4; ++r) {
            int n = q0 + wq * 16 + qd * 4 + r;
            ((ushort_t*)aoT)[((size_t)bi * NN + n) * CC + h * HD + t * 16 + ln] =
                f2us(O[t][r] * inv[r]);
        }
    }
}

// ---------------- Proj GEMM + bias + residual: 64x64 tile, BK=64 single-buffered.
// (unchanged from round 13/14)
__global__ __launch_bounds__(256) void proj_gemm(const bf16* __restrict__ aoT,
                                                 const ushort_t* __restrict__ wB,
                                                 const float* __restrict__ bias,
                                                 const float* __restrict__ xres,
                                                 float* __restrict__ out) {
    __shared__ ushort_t Wl[64 * 64];   // [c_out][k] 128B rows, 8 KB
    __shared__ ushort_t Xl[64 * 64];   // [n][k] 128B rows, 8 KB
    int b  = blockIdx.z;
    int o0 = blockIdx.y * 64;
    int n0 = blockIdx.x * 64;
    int tid = threadIdx.x;
    int wv = tid >> 6, l = tid & 63, ln = l & 15, qd = (l >> 4) & 3;
    int wm = wv >> 1, wn = wv & 1;

    // staging: wave wv stages rows [16wv, 16wv+16) per array, 2 GLD16 calls of 8 rows.
    int strow = wv * 16 + (l >> 3);          // call c adds 8
    int sgran = (l & 7) ^ (l >> 3);          // source granule pre-swizzle
    const ushort_t* xsrc = (const ushort_t*)aoT + ((size_t)b * NN + n0 + strow) * CC + sgran * 8;
    const ushort_t* wsrc = wB + (size_t)(o0 + strow) * CC + sgran * 8;

    floatx4 acc[2][2];
#pragma unroll
    for (int i = 0; i < 2; ++i)
#pragma unroll
        for (int j = 0; j < 2; ++j) acc[i][j] = (floatx4){0.f, 0.f, 0.f, 0.f};

    for (int k0 = 0; k0 < CC; k0 += 64) {
#pragma unroll
        for (int c = 0; c < 2; ++c) {
            GLD16(wsrc + k0 + (size_t)c * 8 * CC, &Wl[(wv * 16 + c * 8) * 64]);
            GLD16(xsrc + k0 + (size_t)c * 8 * CC, &Xl[(wv * 16 + c * 8) * 64]);
        }
        __syncthreads();   // drains vmcnt -> DMA complete
#pragma unroll
        for (int kk = 0; kk < 2; ++kk) {
            int qs = ((kk * 4 + qd) ^ (ln & 7)) * 8;
            bf16x8 af[2], bfr[2];
#pragma unroll
            for (int i = 0; i < 2; ++i)
                af[i] = *(const bf16x8*)&Wl[(wm * 32 + i * 16 + ln) * 64 + qs];
#pragma unroll
            for (int j = 0; j < 2; ++j)
                bfr[j] = *(const bf16x8*)&Xl[(wn * 32 + j * 16 + ln) * 64 + qs];
#pragma unroll
            for (int i = 0; i < 2; ++i)
#pragma unroll
                for (int j = 0; j < 2; ++j)
                    acc[i][j] = __builtin_amdgcn_mfma_f32_16x16x32_bf16(af[i], bfr[j], acc[i][j], 0, 0, 0);
        }
        __syncthreads();
    }

#pragma unroll
    for (int i = 0; i < 2; ++i) {
#pragma unroll
        for (int r = 0; r < 4; ++r) {
            int o = o0 + wm * 32 + i * 16 + qd * 4 + r;
            float bb = bias[o];
            size_t rb = ((size_t)b * CC + o) * NN + n0 + wn * 32 + ln;
#pragma unroll
            for (int j = 0; j < 2; ++j)
                out[rb + j * 16] = acc[i][j][r] + bb + xres[rb + j * 16];
        }
    }
}

extern "C" void kernel_launch(void* const* d_in, const int* in_sizes, int n_in,
                              void* d_out, int out_size, void* d_ws, size_t ws_size,
                              hipStream_t stream) {
    const float* x      = (const float*)d_in[0];
    const float* gamma  = (const float*)d_in[1];
    const float* beta   = (const float*)d_in[2];
    const float* w_qkv  = (const float*)d_in[3];
    const float* b_qkv  = (const float*)d_in[4];
    const float* w_proj = (const float*)d_in[5];
    const float* b_proj = (const float*)d_in[6];
    float* out = (float*)d_out;

    // Workspace (bf16): xnT 8 MB | qkT 16 MB | vN 8 MB | wqkvB 1.5 MB | wprojB 0.5 MB.
    bf16* xnT = (bf16*)d_ws;                       // [b][n][c]
    bf16* qkT = xnT + (size_t)BB * CC * NN;        // [b][n][1024] (Q|K)
    bf16* vN  = qkT + (size_t)BB * NN * QKLD;      // [b][c][n]
    ushort_t* wqkvB  = (ushort_t*)(vN + (size_t)BB * CC * NN);  // [1536][512] bf16
    ushort_t* wprojB = wqkvB + (size_t)C3 * CC;                 // [512][512] bf16
    bf16* aoT = xnT;                               // [b][n][c], reuse

    gn_kernel<<<512, 1024, 0, stream>>>(x, gamma, beta, xnT,
                                        w_qkv, w_proj, wqkvB, wprojB);
    qkv_gemm<<<dim3(NN / 128, C3 / 128, BB), 256, 0, stream>>>(wqkvB, xnT, b_qkv, qkT, vN);
    attn_kernel<<<dim3(NH, NN / 64, BB), 256, 0, stream>>>(qkT, vN, aoT);
    proj_gemm<<<dim3(NN / 64, CC / 64, BB), 256, 0, stream>>>(aoT, wprojB, b_proj, x, out);
}

// Round 16
// 151.173 us; speedup vs baseline: 1.0241x; 1.0110x over previous
//
#include <hip/hip_runtime.h>
#include <hip/hip_bf16.h>

#define BB 8
#define CC 512
#define NN 1024   // H*W
#define NG 32
#define CPG 16
#define NH 8
#define HD 64
#define C3 1536
#define QKLD 1024  // row length of qkT [n][o2], o2 in [0,1024): Q then K

typedef __hip_bfloat16 bf16;
typedef unsigned short ushort_t;

typedef __attribute__((ext_vector_type(8))) short bf16x8;
typedef __attribute__((ext_vector_type(8))) unsigned short ushortx8;
typedef __attribute__((ext_vector_type(4))) float floatx4;

__device__ __forceinline__ float b2f(bf16 h) { return __bfloat162float(h); }
__device__ __forceinline__ bf16 f2b(float f) { return __float2bfloat16(f); }
__device__ __forceinline__ ushort_t f2us(float f) {
    bf16 h = __float2bfloat16(f);
    return *(ushort_t*)&h;
}

#if __has_builtin(__builtin_amdgcn_exp2f)
#define EXP2F(x) __builtin_amdgcn_exp2f(x)
#else
#define EXP2F(x) exp2f(x)
#endif

// global_load_lds width=16: gsrc per-lane global addr; ldst wave-uniform LDS base,
// HW writes ldst + lane*16.
#define GLD16(gsrc, ldst)                                                        \
    __builtin_amdgcn_global_load_lds(                                            \
        (const __attribute__((address_space(1))) unsigned int*)(const void*)(gsrc), \
        (__attribute__((address_space(3))) unsigned int*)(void*)(ldst), 16, 0, 0)

// ---------------- GroupNorm, 1024-thread blocks. (unchanged) ----------------
__global__ __launch_bounds__(1024, 1) void gn_kernel(const float* __restrict__ x,
                                                     const float* __restrict__ gamma,
                                                     const float* __restrict__ beta,
                                                     bf16* __restrict__ xnT,
                                                     const float* __restrict__ wqkv,
                                                     const float* __restrict__ wproj,
                                                     ushort_t* __restrict__ wqkvB,
                                                     ushort_t* __restrict__ wprojB) {
    int tid = threadIdx.x;
    if (blockIdx.x >= 256) {
        // 192 blocks -> wqkv (192*4096 = C3*CC), 64 blocks -> wproj (64*4096 = CC*CC)
        int wb = blockIdx.x - 256;
        const float* src;
        ushort_t* dst;
        int base;
        if (wb < 192) { src = wqkv; dst = wqkvB; base = wb * 4096; }
        else          { src = wproj; dst = wprojB; base = (wb - 192) * 4096; }
        int o = base + tid * 4;
        float4 f = *(const float4*)(src + o);
        ushort_t u[4] = {f2us(f.x), f2us(f.y), f2us(f.z), f2us(f.w)};
        *(uint2*)(dst + o) = *(uint2*)u;
        return;
    }

    const int GSZ = CPG * NN;  // 16384, contiguous per group
    int b = blockIdx.x >> 5;
    int g = blockIdx.x & 31;
    size_t base = ((size_t)b * CC + (size_t)g * CPG) * NN;

    int c_loc = tid >> 6;            // 0..15
    int nsp   = (tid & 63) * 16;     // n sub-span 0..1008
    const float* srcp = x + base + (size_t)c_loc * NN + nsp;

    float fv[16];
    *(float4*)(fv + 0)  = *(const float4*)(srcp + 0);
    *(float4*)(fv + 4)  = *(const float4*)(srcp + 4);
    *(float4*)(fv + 8)  = *(const float4*)(srcp + 8);
    *(float4*)(fv + 12) = *(const float4*)(srcp + 12);
    float s = 0.f, s2 = 0.f;
#pragma unroll
    for (int j = 0; j < 16; ++j) { float v = fv[j]; s += v; s2 += v * v; }

#pragma unroll
    for (int off = 32; off > 0; off >>= 1) {
        s  += __shfl_down(s, off, 64);
        s2 += __shfl_down(s2, off, 64);
    }
    __shared__ float rs[16], rs2[16], stat[2];
    __shared__ ushort_t Lt[16][1032];  // [c][n + 8 pad], 33 KB
    int wid = tid >> 6, lane = tid & 63;
    if (lane == 0) { rs[wid] = s; rs2[wid] = s2; }
    __syncthreads();
    if (tid == 0) {
        float ts = 0.f, ts2 = 0.f;
#pragma unroll
        for (int w = 0; w < 16; ++w) { ts += rs[w]; ts2 += rs2[w]; }
        float mean = ts * (1.f / GSZ);
        float var  = ts2 * (1.f / GSZ) - mean * mean;
        stat[0] = mean;
        stat[1] = rsqrtf(var + 1e-5f);
    }
    __syncthreads();
    float mean = stat[0], inv = stat[1];

    float ga = gamma[g * CPG + c_loc];
    float be = beta[g * CPG + c_loc];

    ushortx8 u0, u1;
#pragma unroll
    for (int j = 0; j < 8; ++j) {
        u0[j] = f2us((fv[j]     - mean) * inv * ga + be);
        u1[j] = f2us((fv[j + 8] - mean) * inv * ga + be);
    }
    *(ushortx8*)&Lt[c_loc][nsp]     = u0;
    *(ushortx8*)&Lt[c_loc][nsp + 8] = u1;
    __syncthreads();

    ushort_t o16[16];
#pragma unroll
    for (int c = 0; c < 16; ++c) o16[c] = Lt[c][tid];
    ushort_t* dst = (ushort_t*)xnT + ((size_t)b * NN + tid) * CC + g * CPG;
    *(uint4*)dst       = *(const uint4*)(o16);
    *(uint4*)(dst + 8) = *(const uint4*)(o16 + 8);
}

// ---------------- QKV GEMM: 128x128 tile, BK=32 double-buffered global_load_lds with
// T4 counted-vmcnt pipeline + T5 s_setprio around the MFMA cluster. (unchanged)
__global__ __launch_bounds__(256) void qkv_gemm(const ushort_t* __restrict__ wB,
                                                const bf16* __restrict__ xnT,
                                                const float* __restrict__ bias,
                                                bf16* __restrict__ qkT,
                                                bf16* __restrict__ vN) {
    __shared__ ushort_t Wl[2][128 * 32];  // [buf][o][k] linear, 16 KB
    __shared__ ushort_t Xl[2][128 * 32];  // [buf][n][k] linear, 16 KB
    int b  = blockIdx.z;
    int o0 = blockIdx.y * 128;
    int n0 = blockIdx.x * 128;
    int tid = threadIdx.x;
    int wv = tid >> 6, l = tid & 63, ln = l & 15, qd = (l >> 4) & 3;
    int wm = wv >> 1, wn = wv & 1;

    int strow = wv * 32 + (l >> 2);          // call-0 row; call-1 adds 16
    int sgran = (l & 3) ^ ((l >> 2) & 3);    // source granule pre-swizzle
    const ushort_t* wsrc = wB + (size_t)(o0 + strow) * CC + sgran * 8;
    const ushort_t* xsrc = (const ushort_t*)xnT + ((size_t)b * NN + n0 + strow) * CC + sgran * 8;
    int lr0 = (wv * 32) * 32;
    int lr1 = (wv * 32 + 16) * 32;

#define QKV_STAGE(t, bf)                                         \
    do {                                                         \
        int ko_ = (t) * 32;                                      \
        GLD16(wsrc + ko_, &Wl[bf][lr0]);                         \
        GLD16(wsrc + ko_ + 16 * CC, &Wl[bf][lr1]);               \
        GLD16(xsrc + ko_, &Xl[bf][lr0]);                         \
        GLD16(xsrc + ko_ + 16 * CC, &Xl[bf][lr1]);               \
    } while (0)

    floatx4 acc[4][4];
#pragma unroll
    for (int i = 0; i < 4; ++i)
#pragma unroll
        for (int j = 0; j < 4; ++j) acc[i][j] = (floatx4){0.f, 0.f, 0.f, 0.f};

    int qs = (qd ^ (ln & 3)) * 8;            // swizzled fragment granule offset

    QKV_STAGE(0, 0);
    QKV_STAGE(1, 1);

    for (int kt = 0; kt < 16; ++kt) {
        if (kt < 15) { asm volatile("s_waitcnt vmcnt(4)" ::: "memory"); }
        else         { asm volatile("s_waitcnt vmcnt(0)" ::: "memory"); }
        __builtin_amdgcn_s_barrier();        // join: every wave's tile-kt DMA complete
        int cb = kt & 1;
        bf16x8 af[4], bfr[4];
#pragma unroll
        for (int i = 0; i < 4; ++i)
            af[i] = *(const bf16x8*)&Wl[cb][(wm * 64 + i * 16 + ln) * 32 + qs];
#pragma unroll
        for (int j = 0; j < 4; ++j)
            bfr[j] = *(const bf16x8*)&Xl[cb][(wn * 64 + j * 16 + ln) * 32 + qs];
        __builtin_amdgcn_s_setprio(1);
#pragma unroll
        for (int i = 0; i < 4; ++i)
#pragma unroll
            for (int j = 0; j < 4; ++j)
                acc[i][j] = __builtin_amdgcn_mfma_f32_16x16x32_bf16(af[i], bfr[j], acc[i][j], 0, 0, 0);
        __builtin_amdgcn_s_setprio(0);
        __builtin_amdgcn_s_barrier();        // all reads of buf[cb] done
        if (kt + 2 < 16) QKV_STAGE(kt + 2, cb);
    }
#undef QKV_STAGE

    if (o0 < 1024) {
#pragma unroll
        for (int i = 0; i < 4; ++i) {
            int ob = o0 + wm * 64 + i * 16 + qd * 4;
            float sc = (ob < 512) ? 0.18033688011112042f : 1.0f;  // 0.125 * log2(e)
#pragma unroll
            for (int j = 0; j < 4; ++j) {
                int n = n0 + wn * 64 + j * 16 + ln;
                ushort_t pk[4];
#pragma unroll
                for (int r = 0; r < 4; ++r)
                    pk[r] = f2us((acc[i][j][r] + bias[ob + r]) * sc);
                *(uint2*)((ushort_t*)qkT + ((size_t)b * NN + n) * QKLD + ob) = *(uint2*)pk;
            }
        }
    } else {
#pragma unroll
        for (int i = 0; i < 4; ++i) {
#pragma unroll
            for (int r = 0; r < 4; ++r) {
                int o = o0 + wm * 64 + i * 16 + qd * 4 + r;
                float bb = bias[o];
                size_t rb = ((size_t)b * CC + (o - 1024)) * NN + n0 + wn * 64 + ln;
#pragma unroll
                for (int j = 0; j < 4; ++j)
                    vN[rb + j * 16] = f2b(acc[i][j][r] + bb);
            }
        }
    }
}

// ---------------- Flash attention: one block per (h, 64-query tile, b) ----------------
// (unchanged from round 15: T5 setprio around MFMA clusters + raw v_exp_f32)
__global__ __launch_bounds__(256, 4) void attn_kernel(const bf16* __restrict__ qkTp,
                                                      const bf16* __restrict__ vNp,
                                                      bf16* __restrict__ aoT) {
    __shared__ ushort_t Kt[2][64 * 64];   // [buf][key][ch]  (swizzled granules)
    __shared__ ushort_t Vn[2][64 * 64];   // [buf][ch][key]  (swizzled granules)
    __shared__ ushort_t Pw[4][16 * 64];   // per-wave [q][key] (swizzled granules)

    int h  = blockIdx.x;        // head (XCD affinity: blockid%8 == h)
    int qt = blockIdx.y;        // query tile 0..15
    int bi = blockIdx.z;
    int q0 = qt * 64;
    int tid = threadIdx.x;
    int wq = tid >> 6;          // wave id: owns queries wq*16..+15
    int l  = tid & 63;
    int ln = l & 15;
    int qd = (l >> 4) & 3;      // quad
    int l7 = ln & 7;
    int lb = ln >> 3;           // 0/1

    const ushort_t* qkT = (const ushort_t*)qkTp;
    const ushort_t* vN  = (const ushort_t*)vNp;

    const ushort_t* qsrc = qkT + ((size_t)bi * NN + q0 + wq * 16 + ln) * QKLD + h * HD + qd * 8;
    bf16x8 aq0 = *(const bf16x8*)(qsrc);
    bf16x8 aq1 = *(const bf16x8*)(qsrc + 32);

    bf16x8 ones;
#pragma unroll
    for (int j = 0; j < 8; ++j) ones[j] = (short)0x3F80;  // bf16 1.0

    floatx4 O[4];
#pragma unroll
    for (int t = 0; t < 4; ++t) O[t] = (floatx4){0.f, 0.f, 0.f, 0.f};
    floatx4 lsum = (floatx4){0.f, 0.f, 0.f, 0.f};

    ushort_t* Pme = &Pw[wq][0];

    int ksl0 = (qd ^ l7) * 8;
    int ksl1 = ((qd + 4) ^ l7) * 8;

    int srow = tid >> 2;            // 0..63
    int g1   = tid & 3;             // granules g1, g1+4
    int s7   = srow & 7;
    int ko1  = (g1 ^ s7) * 8;
    int ko2  = ((g1 + 4) ^ s7) * 8;
    const ushort_t* ks = qkT + ((size_t)bi * NN + srow) * QKLD + 512 + h * HD + g1 * 8;
    const ushort_t* vs = vN + ((size_t)bi * CC + h * HD + srow) * NN + g1 * 8;

    uint4 kr0 = *(const uint4*)(ks);
    uint4 kr1 = *(const uint4*)(ks + 32);
    uint4 vr0 = *(const uint4*)(vs);
    uint4 vr1 = *(const uint4*)(vs + 32);
    {
        ushort_t* kd = &Kt[0][srow * 64];
        *(uint4*)(kd + ko1) = kr0; *(uint4*)(kd + ko2) = kr1;
        ushort_t* vd = &Vn[0][srow * 64];
        *(uint4*)(vd + ko1) = vr0; *(uint4*)(vd + ko2) = vr1;
    }
    kr0 = *(const uint4*)(ks + (size_t)64 * QKLD);
    kr1 = *(const uint4*)(ks + (size_t)64 * QKLD + 32);
    vr0 = *(const uint4*)(vs + 64);
    vr1 = *(const uint4*)(vs + 64 + 32);
    __syncthreads();

    for (int it = 0; it < 16; ++it) {
        int cur = it & 1;
        const ushort_t* KtC = &Kt[cur][0];
        const ushort_t* VnC = &Vn[cur][0];
        if (it < 15) {
            ushort_t* kd = &Kt[cur ^ 1][srow * 64];
            *(uint4*)(kd + ko1) = kr0; *(uint4*)(kd + ko2) = kr1;
            ushort_t* vd = &Vn[cur ^ 1][srow * 64];
            *(uint4*)(vd + ko1) = vr0; *(uint4*)(vd + ko2) = vr1;
        }
        if (it < 14) {
            size_t mo = (size_t)(it + 2) * 64;
            kr0 = *(const uint4*)(ks + mo * QKLD);
            kr1 = *(const uint4*)(ks + mo * QKLD + 32);
            vr0 = *(const uint4*)(vs + mo);
            vr1 = *(const uint4*)(vs + mo + 32);
        }

        floatx4 S[4];
        __builtin_amdgcn_s_setprio(1);
#pragma unroll
        for (int t = 0; t < 4; ++t) {
            const ushort_t* krow = KtC + (t * 16 + ln) * 64;
            bf16x8 b0 = *(const bf16x8*)(krow + ksl0);
            bf16x8 b1 = *(const bf16x8*)(krow + ksl1);
            floatx4 acc = (floatx4){0.f, 0.f, 0.f, 0.f};
            acc = __builtin_amdgcn_mfma_f32_16x16x32_bf16(aq0, b0, acc, 0, 0, 0);
            acc = __builtin_amdgcn_mfma_f32_16x16x32_bf16(aq1, b1, acc, 0, 0, 0);
            S[t] = acc;
        }
        __builtin_amdgcn_s_setprio(0);

#pragma unroll
        for (int t = 0; t < 4; ++t) {
#pragma unroll
            for (int r = 0; r < 4; ++r) {
                float p = EXP2F(S[t][r]);
                int qr = qd * 4 + r;
                Pme[qr * 64 + ((t * 2 + lb) ^ (qr & 7)) * 8 + l7] = f2us(p);
            }
        }
        bf16x8 pa0 = *(const bf16x8*)&Pme[ln * 64 + ksl0];
        bf16x8 pa1 = *(const bf16x8*)&Pme[ln * 64 + ksl1];

        __builtin_amdgcn_s_setprio(1);
        lsum = __builtin_amdgcn_mfma_f32_16x16x32_bf16(pa0, ones, lsum, 0, 0, 0);
        lsum = __builtin_amdgcn_mfma_f32_16x16x32_bf16(pa1, ones, lsum, 0, 0, 0);

#pragma unroll
        for (int t = 0; t < 4; ++t) {
            const ushort_t* vrow = VnC + (t * 16 + ln) * 64;
            bf16x8 v0 = *(const bf16x8*)(vrow + ksl0);
            bf16x8 v1 = *(const bf16x8*)(vrow + ksl1);
            O[t] = __builtin_amdgcn_mfma_f32_16x16x32_bf16(pa0, v0, O[t], 0, 0, 0);
            O[t] = __builtin_amdgcn_mfma_f32_16x16x32_bf16(pa1, v1, O[t], 0, 0, 0);
        }
        __builtin_amdgcn_s_setprio(0);
        if (it < 15) __syncthreads();
    }

    float inv[4];
#pragma unroll
    for (int r = 0; r < 4; ++r) inv[r] = 1.f / lsum[r];
#pragma unroll
    for (int t = 0; t < 4; ++t) {
#pragma unroll
        for (int r = 0; r < 4; ++r) {
            int n = q0 + wq * 16 + qd * 4 + r;
            ((ushort_t*)aoT)[((size_t)bi * NN + n) * CC + h * HD + t * 16 + ln] =
                f2us(O[t][r] * inv[r]);
        }
    }
}

// ---------------- Proj GEMM + bias + residual: 64x64 tile, BK=64 single-buffered
// + T5 s_setprio around the MFMA cluster (the one MFMA kernel not yet covered;
// 4 independent blocks/CU -> same precondition that paid on attn in round 15).
__global__ __launch_bounds__(256) void proj_gemm(const bf16* __restrict__ aoT,
                                                 const ushort_t* __restrict__ wB,
                                                 const float* __restrict__ bias,
                                                 const float* __restrict__ xres,
                                                 float* __restrict__ out) {
    __shared__ ushort_t Wl[64 * 64];   // [c_out][k] 128B rows, 8 KB
    __shared__ ushort_t Xl[64 * 64];   // [n][k] 128B rows, 8 KB
    int b  = blockIdx.z;
    int o0 = blockIdx.y * 64;
    int n0 = blockIdx.x * 64;
    int tid = threadIdx.x;
    int wv = tid >> 6, l = tid & 63, ln = l & 15, qd = (l >> 4) & 3;
    int wm = wv >> 1, wn = wv & 1;

    // staging: wave wv stages rows [16wv, 16wv+16) per array, 2 GLD16 calls of 8 rows.
    int strow = wv * 16 + (l >> 3);          // call c adds 8
    int sgran = (l & 7) ^ (l >> 3);          // source granule pre-swizzle
    const ushort_t* xsrc = (const ushort_t*)aoT + ((size_t)b * NN + n0 + strow) * CC + sgran * 8;
    const ushort_t* wsrc = wB + (size_t)(o0 + strow) * CC + sgran * 8;

    floatx4 acc[2][2];
#pragma unroll
    for (int i = 0; i < 2; ++i)
#pragma unroll
        for (int j = 0; j < 2; ++j) acc[i][j] = (floatx4){0.f, 0.f, 0.f, 0.f};

    for (int k0 = 0; k0 < CC; k0 += 64) {
#pragma unroll
        for (int c = 0; c < 2; ++c) {
            GLD16(wsrc + k0 + (size_t)c * 8 * CC, &Wl[(wv * 16 + c * 8) * 64]);
            GLD16(xsrc + k0 + (size_t)c * 8 * CC, &Xl[(wv * 16 + c * 8) * 64]);
        }
        __syncthreads();   // drains vmcnt -> DMA complete
#pragma unroll
        for (int kk = 0; kk < 2; ++kk) {
            int qs = ((kk * 4 + qd) ^ (ln & 7)) * 8;
            bf16x8 af[2], bfr[2];
#pragma unroll
            for (int i = 0; i < 2; ++i)
                af[i] = *(const bf16x8*)&Wl[(wm * 32 + i * 16 + ln) * 64 + qs];
#pragma unroll
            for (int j = 0; j < 2; ++j)
                bfr[j] = *(const bf16x8*)&Xl[(wn * 32 + j * 16 + ln) * 64 + qs];
            __builtin_amdgcn_s_setprio(1);
#pragma unroll
            for (int i = 0; i < 2; ++i)
#pragma unroll
                for (int j = 0; j < 2; ++j)
                    acc[i][j] = __builtin_amdgcn_mfma_f32_16x16x32_bf16(af[i], bfr[j], acc[i][j], 0, 0, 0);
            __builtin_amdgcn_s_setprio(0);
        }
        __syncthreads();
    }

#pragma unroll
    for (int i = 0; i < 2; ++i) {
#pragma unroll
        for (int r = 0; r < 4; ++r) {
            int o = o0 + wm * 32 + i * 16 + qd * 4 + r;
            float bb = bias[o];
            size_t rb = ((size_t)b * CC + o) * NN + n0 + wn * 32 + ln;
#pragma unroll
            for (int j = 0; j < 2; ++j)
                out[rb + j * 16] = acc[i][j][r] + bb + xres[rb + j * 16];
        }
    }
}

extern "C" void kernel_launch(void* const* d_in, const int* in_sizes, int n_in,
                              void* d_out, int out_size, void* d_ws, size_t ws_size,
                              hipStream_t stream) {
    const float* x      = (const float*)d_in[0];
    const float* gamma  = (const float*)d_in[1];
    const float* beta   = (const float*)d_in[2];
    const float* w_qkv  = (const float*)d_in[3];
    const float* b_qkv  = (const float*)d_in[4];
    const float* w_proj = (const float*)d_in[5];
    const float* b_proj = (const float*)d_in[6];
    float* out = (float*)d_out;

    // Workspace (bf16): xnT 8 MB | qkT 16 MB | vN 8 MB | wqkvB 1.5 MB | wprojB 0.5 MB.
    bf16* xnT = (bf16*)d_ws;                       // [b][n][c]
    bf16* qkT = xnT + (size_t)BB * CC * NN;        // [b][n][1024] (Q|K)
    bf16* vN  = qkT + (size_t)BB * NN * QKLD;      // [b][c][n]
    ushort_t* wqkvB  = (ushort_t*)(vN + (size_t)BB * CC * NN);  // [1536][512] bf16
    ushort_t* wprojB = wqkvB + (size_t)C3 * CC;                 // [512][512] bf16
    bf16* aoT = xnT;                               // [b][n][c], reuse

    gn_kernel<<<512, 1024, 0, stream>>>(x, gamma, beta, xnT,
                                        w_qkv, w_proj, wqkvB, wprojB);
    qkv_gemm<<<dim3(NN / 128, C3 / 128, BB), 256, 0, stream>>>(wqkvB, xnT, b_qkv, qkT, vN);
    attn_kernel<<<dim3(NH, NN / 64, BB), 256, 0, stream>>>(qkT, vN, aoT);
    proj_gemm<<<dim3(NN / 64, CC / 64, BB), 256, 0, stream>>>(aoT, wprojB, b_proj, x, out);
}

// Round 17
// 150.902 us; speedup vs baseline: 1.0259x; 1.0018x over previous
//
#include <hip/hip_runtime.h>
#include <hip/hip_bf16.h>

#define BB 8
#define CC 512
#define NN 1024   // H*W
#define NG 32
#define CPG 16
#define NH 8
#define HD 64
#define C3 1536
#define QKLD 1024  // row length of qkT [n][o2], o2 in [0,1024): Q then K

typedef __hip_bfloat16 bf16;
typedef unsigned short ushort_t;

typedef __attribute__((ext_vector_type(8))) short bf16x8;
typedef __attribute__((ext_vector_type(8))) unsigned short ushortx8;
typedef __attribute__((ext_vector_type(4))) float floatx4;

__device__ __forceinline__ float b2f(bf16 h) { return __bfloat162float(h); }
__device__ __forceinline__ bf16 f2b(float f) { return __float2bfloat16(f); }
__device__ __forceinline__ ushort_t f2us(float f) {
    bf16 h = __float2bfloat16(f);
    return *(ushort_t*)&h;
}

#if __has_builtin(__builtin_amdgcn_exp2f)
#define EXP2F(x) __builtin_amdgcn_exp2f(x)
#else
#define EXP2F(x) exp2f(x)
#endif

// Barrier that drains ONLY LDS ops (lgkmcnt) -- leaves global prefetch loads (vmcnt)
// in flight across the barrier. Cross-wave contract: my ds_writes visible before
// others' ds_reads. The in-flight vmcnt loads are consumed only by this wave's own
// later register uses (compiler auto-inserts precise vmcnt waits).
#define LGKM_BARRIER()                                            \
    do {                                                          \
        asm volatile("s_waitcnt lgkmcnt(0)" ::: "memory");        \
        __builtin_amdgcn_s_barrier();                             \
    } while (0)

// global_load_lds width=16: gsrc per-lane global addr; ldst wave-uniform LDS base,
// HW writes ldst + lane*16.
#define GLD16(gsrc, ldst)                                                        \
    __builtin_amdgcn_global_load_lds(                                            \
        (const __attribute__((address_space(1))) unsigned int*)(const void*)(gsrc), \
        (__attribute__((address_space(3))) unsigned int*)(void*)(ldst), 16, 0, 0)

// ---------------- GroupNorm, 1024-thread blocks. (unchanged) ----------------
__global__ __launch_bounds__(1024, 1) void gn_kernel(const float* __restrict__ x,
                                                     const float* __restrict__ gamma,
                                                     const float* __restrict__ beta,
                                                     bf16* __restrict__ xnT,
                                                     const float* __restrict__ wqkv,
                                                     const float* __restrict__ wproj,
                                                     ushort_t* __restrict__ wqkvB,
                                                     ushort_t* __restrict__ wprojB) {
    int tid = threadIdx.x;
    if (blockIdx.x >= 256) {
        // 192 blocks -> wqkv (192*4096 = C3*CC), 64 blocks -> wproj (64*4096 = CC*CC)
        int wb = blockIdx.x - 256;
        const float* src;
        ushort_t* dst;
        int base;
        if (wb < 192) { src = wqkv; dst = wqkvB; base = wb * 4096; }
        else          { src = wproj; dst = wprojB; base = (wb - 192) * 4096; }
        int o = base + tid * 4;
        float4 f = *(const float4*)(src + o);
        ushort_t u[4] = {f2us(f.x), f2us(f.y), f2us(f.z), f2us(f.w)};
        *(uint2*)(dst + o) = *(uint2*)u;
        return;
    }

    const int GSZ = CPG * NN;  // 16384, contiguous per group
    int b = blockIdx.x >> 5;
    int g = blockIdx.x & 31;
    size_t base = ((size_t)b * CC + (size_t)g * CPG) * NN;

    int c_loc = tid >> 6;            // 0..15
    int nsp   = (tid & 63) * 16;     // n sub-span 0..1008
    const float* srcp = x + base + (size_t)c_loc * NN + nsp;

    float fv[16];
    *(float4*)(fv + 0)  = *(const float4*)(srcp + 0);
    *(float4*)(fv + 4)  = *(const float4*)(srcp + 4);
    *(float4*)(fv + 8)  = *(const float4*)(srcp + 8);
    *(float4*)(fv + 12) = *(const float4*)(srcp + 12);
    float s = 0.f, s2 = 0.f;
#pragma unroll
    for (int j = 0; j < 16; ++j) { float v = fv[j]; s += v; s2 += v * v; }

#pragma unroll
    for (int off = 32; off > 0; off >>= 1) {
        s  += __shfl_down(s, off, 64);
        s2 += __shfl_down(s2, off, 64);
    }
    __shared__ float rs[16], rs2[16], stat[2];
    __shared__ ushort_t Lt[16][1032];  // [c][n + 8 pad], 33 KB
    int wid = tid >> 6, lane = tid & 63;
    if (lane == 0) { rs[wid] = s; rs2[wid] = s2; }
    __syncthreads();
    if (tid == 0) {
        float ts = 0.f, ts2 = 0.f;
#pragma unroll
        for (int w = 0; w < 16; ++w) { ts += rs[w]; ts2 += rs2[w]; }
        float mean = ts * (1.f / GSZ);
        float var  = ts2 * (1.f / GSZ) - mean * mean;
        stat[0] = mean;
        stat[1] = rsqrtf(var + 1e-5f);
    }
    __syncthreads();
    float mean = stat[0], inv = stat[1];

    float ga = gamma[g * CPG + c_loc];
    float be = beta[g * CPG + c_loc];

    ushortx8 u0, u1;
#pragma unroll
    for (int j = 0; j < 8; ++j) {
        u0[j] = f2us((fv[j]     - mean) * inv * ga + be);
        u1[j] = f2us((fv[j + 8] - mean) * inv * ga + be);
    }
    *(ushortx8*)&Lt[c_loc][nsp]     = u0;
    *(ushortx8*)&Lt[c_loc][nsp + 8] = u1;
    __syncthreads();

    ushort_t o16[16];
#pragma unroll
    for (int c = 0; c < 16; ++c) o16[c] = Lt[c][tid];
    ushort_t* dst = (ushort_t*)xnT + ((size_t)b * NN + tid) * CC + g * CPG;
    *(uint4*)dst       = *(const uint4*)(o16);
    *(uint4*)(dst + 8) = *(const uint4*)(o16 + 8);
}

// ---------------- QKV GEMM: 128x128 tile, BK=32 double-buffered global_load_lds with
// T4 counted-vmcnt pipeline + T5 s_setprio around the MFMA cluster. (unchanged)
__global__ __launch_bounds__(256) void qkv_gemm(const ushort_t* __restrict__ wB,
                                                const bf16* __restrict__ xnT,
                                                const float* __restrict__ bias,
                                                bf16* __restrict__ qkT,
                                                bf16* __restrict__ vN) {
    __shared__ ushort_t Wl[2][128 * 32];  // [buf][o][k] linear, 16 KB
    __shared__ ushort_t Xl[2][128 * 32];  // [buf][n][k] linear, 16 KB
    int b  = blockIdx.z;
    int o0 = blockIdx.y * 128;
    int n0 = blockIdx.x * 128;
    int tid = threadIdx.x;
    int wv = tid >> 6, l = tid & 63, ln = l & 15, qd = (l >> 4) & 3;
    int wm = wv >> 1, wn = wv & 1;

    int strow = wv * 32 + (l >> 2);          // call-0 row; call-1 adds 16
    int sgran = (l & 3) ^ ((l >> 2) & 3);    // source granule pre-swizzle
    const ushort_t* wsrc = wB + (size_t)(o0 + strow) * CC + sgran * 8;
    const ushort_t* xsrc = (const ushort_t*)xnT + ((size_t)b * NN + n0 + strow) * CC + sgran * 8;
    int lr0 = (wv * 32) * 32;
    int lr1 = (wv * 32 + 16) * 32;

#define QKV_STAGE(t, bf)                                         \
    do {                                                         \
        int ko_ = (t) * 32;                                      \
        GLD16(wsrc + ko_, &Wl[bf][lr0]);                         \
        GLD16(wsrc + ko_ + 16 * CC, &Wl[bf][lr1]);               \
        GLD16(xsrc + ko_, &Xl[bf][lr0]);                         \
        GLD16(xsrc + ko_ + 16 * CC, &Xl[bf][lr1]);               \
    } while (0)

    floatx4 acc[4][4];
#pragma unroll
    for (int i = 0; i < 4; ++i)
#pragma unroll
        for (int j = 0; j < 4; ++j) acc[i][j] = (floatx4){0.f, 0.f, 0.f, 0.f};

    int qs = (qd ^ (ln & 3)) * 8;            // swizzled fragment granule offset

    QKV_STAGE(0, 0);
    QKV_STAGE(1, 1);

    for (int kt = 0; kt < 16; ++kt) {
        if (kt < 15) { asm volatile("s_waitcnt vmcnt(4)" ::: "memory"); }
        else         { asm volatile("s_waitcnt vmcnt(0)" ::: "memory"); }
        __builtin_amdgcn_s_barrier();        // join: every wave's tile-kt DMA complete
        int cb = kt & 1;
        bf16x8 af[4], bfr[4];
#pragma unroll
        for (int i = 0; i < 4; ++i)
            af[i] = *(const bf16x8*)&Wl[cb][(wm * 64 + i * 16 + ln) * 32 + qs];
#pragma unroll
        for (int j = 0; j < 4; ++j)
            bfr[j] = *(const bf16x8*)&Xl[cb][(wn * 64 + j * 16 + ln) * 32 + qs];
        __builtin_amdgcn_s_setprio(1);
#pragma unroll
        for (int i = 0; i < 4; ++i)
#pragma unroll
            for (int j = 0; j < 4; ++j)
                acc[i][j] = __builtin_amdgcn_mfma_f32_16x16x32_bf16(af[i], bfr[j], acc[i][j], 0, 0, 0);
        __builtin_amdgcn_s_setprio(0);
        __builtin_amdgcn_s_barrier();        // all reads of buf[cb] done
        if (kt + 2 < 16) QKV_STAGE(kt + 2, cb);
    }
#undef QKV_STAGE

    if (o0 < 1024) {
#pragma unroll
        for (int i = 0; i < 4; ++i) {
            int ob = o0 + wm * 64 + i * 16 + qd * 4;
            float sc = (ob < 512) ? 0.18033688011112042f : 1.0f;  // 0.125 * log2(e)
#pragma unroll
            for (int j = 0; j < 4; ++j) {
                int n = n0 + wn * 64 + j * 16 + ln;
                ushort_t pk[4];
#pragma unroll
                for (int r = 0; r < 4; ++r)
                    pk[r] = f2us((acc[i][j][r] + bias[ob + r]) * sc);
                *(uint2*)((ushort_t*)qkT + ((size_t)b * NN + n) * QKLD + ob) = *(uint2*)pk;
            }
        }
    } else {
#pragma unroll
        for (int i = 0; i < 4; ++i) {
#pragma unroll
            for (int r = 0; r < 4; ++r) {
                int o = o0 + wm * 64 + i * 16 + qd * 4 + r;
                float bb = bias[o];
                size_t rb = ((size_t)b * CC + (o - 1024)) * NN + n0 + wn * 64 + ln;
#pragma unroll
                for (int j = 0; j < 4; ++j)
                    vN[rb + j * 16] = f2b(acc[i][j][r] + bb);
            }
        }
    }
}

// ---------------- Flash attention: one block per (h, 64-query tile, b) ----------------
// Round-15/16 structure, with the per-step __syncthreads() replaced by
// LGKM_BARRIER(): drains only LDS ops, leaving the 2-step register prefetch's
// global loads in flight across the barrier (T4 applied where the slack exists).
__global__ __launch_bounds__(256, 4) void attn_kernel(const bf16* __restrict__ qkTp,
                                                      const bf16* __restrict__ vNp,
                                                      bf16* __restrict__ aoT) {
    __shared__ ushort_t Kt[2][64 * 64];   // [buf][key][ch]  (swizzled granules)
    __shared__ ushort_t Vn[2][64 * 64];   // [buf][ch][key]  (swizzled granules)
    __shared__ ushort_t Pw[4][16 * 64];   // per-wave [q][key] (swizzled granules)

    int h  = blockIdx.x;        // head (XCD affinity: blockid%8 == h)
    int qt = blockIdx.y;        // query tile 0..15
    int bi = blockIdx.z;
    int q0 = qt * 64;
    int tid = threadIdx.x;
    int wq = tid >> 6;          // wave id: owns queries wq*16..+15
    int l  = tid & 63;
    int ln = l & 15;
    int qd = (l >> 4) & 3;      // quad
    int l7 = ln & 7;
    int lb = ln >> 3;           // 0/1

    const ushort_t* qkT = (const ushort_t*)qkTp;
    const ushort_t* vN  = (const ushort_t*)vNp;

    const ushort_t* qsrc = qkT + ((size_t)bi * NN + q0 + wq * 16 + ln) * QKLD + h * HD + qd * 8;
    bf16x8 aq0 = *(const bf16x8*)(qsrc);
    bf16x8 aq1 = *(const bf16x8*)(qsrc + 32);

    bf16x8 ones;
#pragma unroll
    for (int j = 0; j < 8; ++j) ones[j] = (short)0x3F80;  // bf16 1.0

    floatx4 O[4];
#pragma unroll
    for (int t = 0; t < 4; ++t) O[t] = (floatx4){0.f, 0.f, 0.f, 0.f};
    floatx4 lsum = (floatx4){0.f, 0.f, 0.f, 0.f};

    ushort_t* Pme = &Pw[wq][0];

    int ksl0 = (qd ^ l7) * 8;
    int ksl1 = ((qd + 4) ^ l7) * 8;

    int srow = tid >> 2;            // 0..63
    int g1   = tid & 3;             // granules g1, g1+4
    int s7   = srow & 7;
    int ko1  = (g1 ^ s7) * 8;
    int ko2  = ((g1 + 4) ^ s7) * 8;
    const ushort_t* ks = qkT + ((size_t)bi * NN + srow) * QKLD + 512 + h * HD + g1 * 8;
    const ushort_t* vs = vN + ((size_t)bi * CC + h * HD + srow) * NN + g1 * 8;

    uint4 kr0 = *(const uint4*)(ks);
    uint4 kr1 = *(const uint4*)(ks + 32);
    uint4 vr0 = *(const uint4*)(vs);
    uint4 vr1 = *(const uint4*)(vs + 32);
    {
        ushort_t* kd = &Kt[0][srow * 64];
        *(uint4*)(kd + ko1) = kr0; *(uint4*)(kd + ko2) = kr1;
        ushort_t* vd = &Vn[0][srow * 64];
        *(uint4*)(vd + ko1) = vr0; *(uint4*)(vd + ko2) = vr1;
    }
    kr0 = *(const uint4*)(ks + (size_t)64 * QKLD);
    kr1 = *(const uint4*)(ks + (size_t)64 * QKLD + 32);
    vr0 = *(const uint4*)(vs + 64);
    vr1 = *(const uint4*)(vs + 64 + 32);
    LGKM_BARRIER();

    for (int it = 0; it < 16; ++it) {
        int cur = it & 1;
        const ushort_t* KtC = &Kt[cur][0];
        const ushort_t* VnC = &Vn[cur][0];
        if (it < 15) {
            ushort_t* kd = &Kt[cur ^ 1][srow * 64];
            *(uint4*)(kd + ko1) = kr0; *(uint4*)(kd + ko2) = kr1;
            ushort_t* vd = &Vn[cur ^ 1][srow * 64];
            *(uint4*)(vd + ko1) = vr0; *(uint4*)(vd + ko2) = vr1;
        }
        if (it < 14) {
            size_t mo = (size_t)(it + 2) * 64;
            kr0 = *(const uint4*)(ks + mo * QKLD);
            kr1 = *(const uint4*)(ks + mo * QKLD + 32);
            vr0 = *(const uint4*)(vs + mo);
            vr1 = *(const uint4*)(vs + mo + 32);
        }

        floatx4 S[4];
        __builtin_amdgcn_s_setprio(1);
#pragma unroll
        for (int t = 0; t < 4; ++t) {
            const ushort_t* krow = KtC + (t * 16 + ln) * 64;
            bf16x8 b0 = *(const bf16x8*)(krow + ksl0);
            bf16x8 b1 = *(const bf16x8*)(krow + ksl1);
            floatx4 acc = (floatx4){0.f, 0.f, 0.f, 0.f};
            acc = __builtin_amdgcn_mfma_f32_16x16x32_bf16(aq0, b0, acc, 0, 0, 0);
            acc = __builtin_amdgcn_mfma_f32_16x16x32_bf16(aq1, b1, acc, 0, 0, 0);
            S[t] = acc;
        }
        __builtin_amdgcn_s_setprio(0);

#pragma unroll
        for (int t = 0; t < 4; ++t) {
#pragma unroll
            for (int r = 0; r < 4; ++r) {
                float p = EXP2F(S[t][r]);
                int qr = qd * 4 + r;
                Pme[qr * 64 + ((t * 2 + lb) ^ (qr & 7)) * 8 + l7] = f2us(p);
            }
        }
        bf16x8 pa0 = *(const bf16x8*)&Pme[ln * 64 + ksl0];
        bf16x8 pa1 = *(const bf16x8*)&Pme[ln * 64 + ksl1];

        __builtin_amdgcn_s_setprio(1);
        lsum = __builtin_amdgcn_mfma_f32_16x16x32_bf16(pa0, ones, lsum, 0, 0, 0);
        lsum = __builtin_amdgcn_mfma_f32_16x16x32_bf16(pa1, ones, lsum, 0, 0, 0);

#pragma unroll
        for (int t = 0; t < 4; ++t) {
            const ushort_t* vrow = VnC + (t * 16 + ln) * 64;
            bf16x8 v0 = *(const bf16x8*)(vrow + ksl0);
            bf16x8 v1 = *(const bf16x8*)(vrow + ksl1);
            O[t] = __builtin_amdgcn_mfma_f32_16x16x32_bf16(pa0, v0, O[t], 0, 0, 0);
            O[t] = __builtin_amdgcn_mfma_f32_16x16x32_bf16(pa1, v1, O[t], 0, 0, 0);
        }
        __builtin_amdgcn_s_setprio(0);
        if (it < 15) LGKM_BARRIER();
    }

    float inv[4];
#pragma unroll
    for (int r = 0; r < 4; ++r) inv[r] = 1.f / lsum[r];
#pragma unroll
    for (int t = 0; t < 4; ++t) {
#pragma unroll
        for (int r = 0; r < 4; ++r) {
            int n = q0 + wq * 16 + qd * 4 + r;
            ((ushort_t*)aoT)[((size_t)bi * NN + n) * CC + h * HD + t * 16 + ln] =
                f2us(O[t][r] * inv[r]);
        }
    }
}

// ---------------- Proj GEMM + bias + residual: 64x64 tile, BK=64 single-buffered
// + T5 s_setprio around the MFMA cluster. (unchanged from round 16)
__global__ __launch_bounds__(256) void proj_gemm(const bf16* __restrict__ aoT,
                                                 const ushort_t* __restrict__ wB,
                                                 const float* __restrict__ bias,
                                                 const float* __restrict__ xres,
                                                 float* __restrict__ out) {
    __shared__ ushort_t Wl[64 * 64];   // [c_out][k] 128B rows, 8 KB
    __shared__ ushort_t Xl[64 * 64];   // [n][k] 128B rows, 8 KB
    int b  = blockIdx.z;
    int o0 = blockIdx.y * 64;
    int n0 = blockIdx.x * 64;
    int tid = threadIdx.x;
    int wv = tid >> 6, l = tid & 63, ln = l & 15, qd = (l >> 4) & 3;
    int wm = wv >> 1, wn = wv & 1;

    // staging: wave wv stages rows [16wv, 16wv+16) per array, 2 GLD16 calls of 8 rows.
    int strow = wv * 16 + (l >> 3);          // call c adds 8
    int sgran = (l & 7) ^ (l >> 3);          // source granule pre-swizzle
    const ushort_t* xsrc = (const ushort_t*)aoT + ((size_t)b * NN + n0 + strow) * CC + sgran * 8;
    const ushort_t* wsrc = wB + (size_t)(o0 + strow) * CC + sgran * 8;

    floatx4 acc[2][2];
#pragma unroll
    for (int i = 0; i < 2; ++i)
#pragma unroll
        for (int j = 0; j < 2; ++j) acc[i][j] = (floatx4){0.f, 0.f, 0.f, 0.f};

    for (int k0 = 0; k0 < CC; k0 += 64) {
#pragma unroll
        for (int c = 0; c < 2; ++c) {
            GLD16(wsrc + k0 + (size_t)c * 8 * CC, &Wl[(wv * 16 + c * 8) * 64]);
            GLD16(xsrc + k0 + (size_t)c * 8 * CC, &Xl[(wv * 16 + c * 8) * 64]);
        }
        __syncthreads();   // drains vmcnt -> DMA complete
#pragma unroll
        for (int kk = 0; kk < 2; ++kk) {
            int qs = ((kk * 4 + qd) ^ (ln & 7)) * 8;
            bf16x8 af[2], bfr[2];
#pragma unroll
            for (int i = 0; i < 2; ++i)
                af[i] = *(const bf16x8*)&Wl[(wm * 32 + i * 16 + ln) * 64 + qs];
#pragma unroll
            for (int j = 0; j < 2; ++j)
                bfr[j] = *(const bf16x8*)&Xl[(wn * 32 + j * 16 + ln) * 64 + qs];
            __builtin_amdgcn_s_setprio(1);
#pragma unroll
            for (int i = 0; i < 2; ++i)
#pragma unroll
                for (int j = 0; j < 2; ++j)
                    acc[i][j] = __builtin_amdgcn_mfma_f32_16x16x32_bf16(af[i], bfr[j], acc[i][j], 0, 0, 0);
            __builtin_amdgcn_s_setprio(0);
        }
        __syncthreads();
    }

#pragma unroll
    for (int i = 0; i < 2; ++i) {
#pragma unroll
        for (int r = 0; r < 4; ++r) {
            int o = o0 + wm * 32 + i * 16 + qd * 4 + r;
            float bb = bias[o];
            size_t rb = ((size_t)b * CC + o) * NN + n0 + wn * 32 + ln;
#pragma unroll
            for (int j = 0; j < 2; ++j)
                out[rb + j * 16] = acc[i][j][r] + bb + xres[rb + j * 16];
        }
    }
}

extern "C" void kernel_launch(void* const* d_in, const int* in_sizes, int n_in,
                              void* d_out, int out_size, void* d_ws, size_t ws_size,
                              hipStream_t stream) {
    const float* x      = (const float*)d_in[0];
    const float* gamma  = (const float*)d_in[1];
    const float* beta   = (const float*)d_in[2];
    const float* w_qkv  = (const float*)d_in[3];
    const float* b_qkv  = (const float*)d_in[4];
    const float* w_proj = (const float*)d_in[5];
    const float* b_proj = (const float*)d_in[6];
    float* out = (float*)d_out;

    // Workspace (bf16): xnT 8 MB | qkT 16 MB | vN 8 MB | wqkvB 1.5 MB | wprojB 0.5 MB.
    bf16* xnT = (bf16*)d_ws;                       // [b][n][c]
    bf16* qkT = xnT + (size_t)BB * CC * NN;        // [b][n][1024] (Q|K)
    bf16* vN  = qkT + (size_t)BB * NN * QKLD;      // [b][c][n]
    ushort_t* wqkvB  = (ushort_t*)(vN + (size_t)BB * CC * NN);  // [1536][512] bf16
    ushort_t* wprojB = wqkvB + (size_t)C3 * CC;                 // [512][512] bf16
    bf16* aoT = xnT;                               // [b][n][c], reuse

    gn_kernel<<<512, 1024, 0, stream>>>(x, gamma, beta, xnT,
                                        w_qkv, w_proj, wqkvB, wprojB);
    qkv_gemm<<<dim3(NN / 128, C3 / 128, BB), 256, 0, stream>>>(wqkvB, xnT, b_qkv, qkT, vN);
    attn_kernel<<<dim3(NH, NN / 64, BB), 256, 0, stream>>>(qkT, vN, aoT);
    proj_gemm<<<dim3(NN / 64, CC / 64, BB), 256, 0, stream>>>(aoT, wprojB, b_proj, x, out);
}